// Round 9
// baseline (9911.607 us; speedup 1.0000x reference)
//
#include <hip/hip_runtime.h>
#include <cmath>

#define NNODES 20000
#define FD 64
#define EPN 15      // regular edges per node
#define NB 1024     // DEG * F
#define BSUB 80     // subspace width (top-64 + 16 buffer)
#define NCLS 16
#define NPAIR 40
#define KSPLIT 16   // R9: split-K depth for the Chebyshev MV chain

// ---------------------------------------------------------------------------
// out[n][o] = relu?( sum_j X[n][j] * W[o][j] + bias[o] ), X: [N,64], W: [ncol,64]
__global__ __launch_bounds__(256) void k_linT(const float* __restrict__ X,
    const float* __restrict__ W, const float* __restrict__ bias,
    float* __restrict__ out, int ncol, int relu)
{
  __shared__ float Wsh[64][65];
  __shared__ float Xsh[64][65];
  int t = threadIdx.x;
  int r0 = blockIdx.x * 64;
  for (int idx = t; idx < ncol * 64; idx += 256) Wsh[idx >> 6][idx & 63] = W[idx];
  for (int idx = t; idx < 64 * 64; idx += 256) {
    int r = idx >> 6, c = idx & 63;
    Xsh[r][c] = (r0 + r < NNODES) ? X[(size_t)(r0 + r) * 64 + c] : 0.f;
  }
  __syncthreads();
  for (int idx = t; idx < 64 * ncol; idx += 256) {
    int r = idx / ncol, o = idx % ncol;
    float acc = 0.f;
    #pragma unroll
    for (int j = 0; j < 64; j++) acc += Xsh[r][j] * Wsh[o][j];
    if (bias) acc += bias[o];
    if (relu) acc = fmaxf(acc, 0.f);
    if (r0 + r < NNODES) out[(size_t)(r0 + r) * ncol + o] = acc;
  }
}

// ---------------------------------------------------------------------------
// fallback: mus from gathered hl (used only when X not materialized)
__global__ __launch_bounds__(256) void k_meanslot(const float* __restrict__ hl,
    const int* __restrict__ src, float* __restrict__ mus)
{
  int k = blockIdx.x;          // slot 0..15
  int part = blockIdx.y;       // 8 parts x 2500 nodes
  int t = threadIdx.x;
  int c = t & 63, sub = t >> 6;
  int d0 = part * 2500;
  float acc = 0.f;
  for (int d = d0 + sub; d < d0 + 2500; d += 4) {
    int row = (k < EPN) ? src[d * EPN + k] : d;
    acc += hl[(size_t)row * 64 + c];
  }
  __shared__ float red[4][64];
  red[sub][c] = acc;
  __syncthreads();
  if (t < 64) {
    float s = red[0][t] + red[1][t] + red[2][t] + red[3][t];
    atomicAdd(&mus[k * 64 + t], s * (1.f / 20000.f));
  }
}

// ---------------------------------------------------------------------------
// Materialize UNCENTERED X[d][k*64+f] = hl[row(d,k)][f]; also accumulates the
// per-column partial sums into mus (LDS atomics; one global add/col/block).
__global__ __launch_bounds__(256) void k_buildX(const float* __restrict__ hl,
    const int* __restrict__ src, float* __restrict__ X, float* __restrict__ mus)
{
  __shared__ float msum[1024];
  int t = threadIdx.x;
  for (int i = t; i < 1024; i += 256) msum[i] = 0.f;
  __syncthreads();
  int d0 = blockIdx.x * 64;
  for (int k = 0; k < 16; k++) {
    float4 acc = make_float4(0.f, 0.f, 0.f, 0.f);
    #pragma unroll
    for (int s = 0; s < 4; s++) {
      int item = t + s * 256;
      int rr = item >> 4, f4 = item & 15;
      int d = d0 + rr;
      if (d < NNODES) {
        int row = (k < EPN) ? src[d * EPN + k] : d;
        float4 v = ((const float4*)hl)[(size_t)row * 16 + f4];
        ((float4*)X)[(size_t)d * 256 + k * 16 + f4] = v;
        acc.x += v.x; acc.y += v.y; acc.z += v.z; acc.w += v.w;
      }
    }
    int base = k * 64 + (t & 15) * 4;
    atomicAdd(&msum[base + 0], acc.x);
    atomicAdd(&msum[base + 1], acc.y);
    atomicAdd(&msum[base + 2], acc.z);
    atomicAdd(&msum[base + 3], acc.w);
  }
  __syncthreads();
  for (int i = t; i < 1024; i += 256)
    if (msum[i] != 0.f) atomicAdd(&mus[i], msum[i] * (1.f / 20000.f));
}

// ---------------------------------------------------------------------------
// SYRK over rows of X (layout: [nrows][256 float4]): TP[kz] = upper 128x128
// tiles of (X - mu)^T (X - mu) over row-slice kz. 8x8 per-thread, conflict-
// free fragments (R3), register-prefetch (R4), bijective XCD-chunk swizzle
// (R8: each XCD's blocks cover a contiguous (slice,tile) range; per-XCD L2
// working set ~1 slice's panels = 4 MB). mus==nullptr -> no centering
// (used for G2 = G^T G). gridDim.x = 36*nslices, divisible by 8.
__global__ __launch_bounds__(256) void k_syrkX(const float* __restrict__ X,
    float* __restrict__ TP, int rows, const float* __restrict__ mus)
{
  __shared__ float As[32][128];
  __shared__ float Bs[32][128];
  __shared__ float muA[128], muB[128];
  int t = threadIdx.x;
  int nb = gridDim.x;
  int f = blockIdx.x;
  int orig = (f & 7) * (nb >> 3) + (f >> 3);   // XCD-chunk swizzle (bijective)
  int kzS = orig / 36;
  int pr = orig % 36;
  int I = 0, rem = pr;
  for (int ii = 0; ii < 8; ii++) {
    int cnt = 8 - ii;
    if (rem < cnt) { I = ii; break; }
    rem -= cnt;
  }
  int J = I + rem;
  if (t < 128) muA[t] = mus ? mus[I * 128 + t] : 0.f;
  else muB[t - 128] = mus ? mus[J * 128 + (t - 128)] : 0.f;
  __syncthreads();
  int d0 = kzS * rows;
  int d1 = d0 + rows;
  int a0 = (t & 15) * 4, b0 = (t >> 4) * 4;
  float4 pa[4], pb[4];
  auto LOADR = [&](int dc) {
    #pragma unroll
    for (int s = 0; s < 4; s++) {
      int idx = t + s * 256;
      int rr = idx >> 5, c4 = idx & 31;
      int d = dc + rr;
      float4 va = make_float4(0.f, 0.f, 0.f, 0.f), vb = va;
      if (d < d1) {
        va = ((const float4*)X)[(size_t)d * 256 + I * 32 + c4];
        vb = ((const float4*)X)[(size_t)d * 256 + J * 32 + c4];
        float4 ma = *(const float4*)&muA[c4 * 4];
        float4 mb = *(const float4*)&muB[c4 * 4];
        va.x -= ma.x; va.y -= ma.y; va.z -= ma.z; va.w -= ma.w;
        vb.x -= mb.x; vb.y -= mb.y; vb.z -= mb.z; vb.w -= mb.w;
      }
      pa[s] = va; pb[s] = vb;
    }
  };
  LOADR(d0);
  float acc[8][8] = {};
  for (int dc = d0; dc < d1; dc += 32) {
    __syncthreads();
    #pragma unroll
    for (int s = 0; s < 4; s++) {
      int idx = t + s * 256;
      int rr = idx >> 5, c4 = idx & 31;
      *(float4*)&As[rr][c4 * 4] = pa[s];
      *(float4*)&Bs[rr][c4 * 4] = pb[s];
    }
    __syncthreads();
    if (dc + 32 < d1) LOADR(dc + 32);
    for (int dd = 0; dd < 32; dd++) {
      float av[8], bv[8];
      *(float4*)&av[0] = *(const float4*)&As[dd][a0];
      *(float4*)&av[4] = *(const float4*)&As[dd][a0 + 64];
      *(float4*)&bv[0] = *(const float4*)&Bs[dd][b0];
      *(float4*)&bv[4] = *(const float4*)&Bs[dd][b0 + 64];
      #pragma unroll
      for (int x = 0; x < 8; x++)
        #pragma unroll
        for (int y = 0; y < 8; y++) acc[x][y] += av[x] * bv[y];
    }
  }
  float* Tout = TP + (size_t)kzS * ((size_t)NB * NB);
  #pragma unroll
  for (int x = 0; x < 8; x++) {
    int rowi = I * 128 + ((x < 4) ? (a0 + x) : (64 + a0 + x - 4));
    size_t base = (size_t)rowi * NB + J * 128;
    *(float4*)&Tout[base + b0]      = make_float4(acc[x][0], acc[x][1], acc[x][2], acc[x][3]);
    *(float4*)&Tout[base + 64 + b0] = make_float4(acc[x][4], acc[x][5], acc[x][6], acc[x][7]);
  }
}

// sum the ns split-K partials + symmetrize + scale. When Sinit != nullptr,
// blocks >= 4096 additionally run cut0 (block 4096) and the S hash-init.
__global__ __launch_bounds__(256) void k_assembleG16(const float* __restrict__ TP,
    float* __restrict__ G, int ns, float scale,
    float* __restrict__ Sinit, const float* __restrict__ Gd,
    double* __restrict__ scal)
{
  int b = blockIdx.x;
  int t = threadIdx.x;
  if (b >= 4096) {
    if (b == 4096) {
      __shared__ float red[256];
      float m = 0.f;
      for (int p = t; p < NB; p += 256) m = fmaxf(m, Gd[(size_t)p * NB + p]);
      red[t] = m;
      __syncthreads();
      for (int s = 128; s; s >>= 1) {
        if (t < s) red[t] = fmaxf(red[t], red[t + s]);
        __syncthreads();
      }
      if (t == 0) {
        double c = 0.9 * (double)red[0];
        scal[0] = c;
        scal[1] = c * c;
      }
    } else {
      int idx = (b - 4097) * 256 + t;
      if (idx < NB * BSUB) {
        unsigned u = (unsigned)(idx + 1) * 2654435761u;
        u ^= u >> 16; u *= 2246822519u; u ^= u >> 13; u *= 3266489917u; u ^= u >> 16;
        Sinit[idx] = ((float)u * (1.f / 4294967296.f)) - 0.5f;
      }
    }
    return;
  }
  size_t idx = (size_t)b * 256 + t;
  int p = (int)(idx >> 10), q = (int)(idx & 1023);
  int ti = p >> 6, tj = q >> 6;
  size_t e = (ti <= tj) ? idx : (((size_t)q << 10) | (size_t)p);
  float v = 0.f;
  for (int s2 = 0; s2 < ns; s2++) v += TP[(size_t)s2 * ((size_t)NB * NB) + e];
  G[idx] = v * scale;
}

// ---------------------------------------------------------------------------
// fallback gram path (used only if workspace too small for X/TP)
__global__ __launch_bounds__(256) void k_gram(const float* __restrict__ hl,
    const int* __restrict__ src, const float* __restrict__ mus,
    float* __restrict__ T)
{
  __shared__ float Ash[64][64];
  __shared__ float Bsh[64][64];
  __shared__ float muA[64], muB[64];
  int t = threadIdx.x;
  int pr = blockIdx.x, i = 0, rem = pr;
  for (int ii = 0; ii < 16; ii++) {
    int cnt = 16 - ii;
    if (rem < cnt) { i = ii; break; }
    rem -= cnt;
  }
  int j = i + rem;
  if (t < 64) muA[t] = mus[i * 64 + t];
  else if (t < 128) muB[t - 64] = mus[j * 64 + (t - 64)];
  float acc[4][4] = {};
  int a0 = (t & 15) * 4, b0 = (t >> 4) * 4;
  int d0 = blockIdx.y * 4000, d1 = d0 + 4000;
  for (int dc = d0; dc < d1; dc += 64) {
    __syncthreads();
    for (int item = t; item < 1024; item += 256) {
      int rr = item >> 4, f4 = item & 15;
      int d = dc + rr;
      float4 va = make_float4(0.f, 0.f, 0.f, 0.f);
      float4 vb = va;
      if (d < d1) {
        int ra = (i < EPN) ? src[d * EPN + i] : d;
        int rb = (j < EPN) ? src[d * EPN + j] : d;
        va = ((const float4*)hl)[(size_t)ra * 16 + f4];
        vb = ((const float4*)hl)[(size_t)rb * 16 + f4];
        int cb = f4 * 4;
        va.x -= muA[cb]; va.y -= muA[cb + 1]; va.z -= muA[cb + 2]; va.w -= muA[cb + 3];
        vb.x -= muB[cb]; vb.y -= muB[cb + 1]; vb.z -= muB[cb + 2]; vb.w -= muB[cb + 3];
      }
      ((float4*)&Ash[rr][0])[f4] = va;
      ((float4*)&Bsh[rr][0])[f4] = vb;
    }
    __syncthreads();
    for (int dd = 0; dd < 64; dd++) {
      float av[4], bv[4];
      #pragma unroll
      for (int u = 0; u < 4; u++) av[u] = Ash[dd][a0 + u];
      #pragma unroll
      for (int u = 0; u < 4; u++) bv[u] = Bsh[dd][b0 + u];
      #pragma unroll
      for (int x = 0; x < 4; x++)
        #pragma unroll
        for (int y = 0; y < 4; y++) acc[x][y] += av[x] * bv[y];
    }
  }
  #pragma unroll
  for (int x = 0; x < 4; x++)
    #pragma unroll
    for (int y = 0; y < 4; y++)
      atomicAdd(&T[(size_t)(i * 64 + a0 + x) * NB + (j * 64 + b0 + y)], acc[x][y]);
}

// ---------------------------------------------------------------------------
__global__ __launch_bounds__(256) void k_assembleG(const float* __restrict__ T,
    float* __restrict__ G)
{
  size_t idx = (size_t)blockIdx.x * 256 + threadIdx.x;
  int p = (int)(idx >> 10), q = (int)(idx & 1023);
  int ti = p >> 6, tj = q >> 6;
  float v = (ti <= tj) ? T[idx] : T[((size_t)q << 10) | (size_t)p];
  G[idx] = v * (1.f / 256.f);
}

// ---------------------------------------------------------------------------
// G2 = G @ G (fallback path only; fast path uses k_syrkX on G).
__global__ __launch_bounds__(256) void k_gemmG2(const float* __restrict__ G,
    float* __restrict__ G2)
{
  __shared__ float Ash[64][68];
  __shared__ float Bsh[64][68];
  int t = threadIdx.x;
  int bi = blockIdx.x * 64, bj = blockIdx.y * 64;
  int a0 = (t & 15) * 4, b0 = (t >> 4) * 4;
  float acc[4][4] = {};
  for (int d0 = 0; d0 < NB; d0 += 64) {
    __syncthreads();
    for (int item = t; item < 1024; item += 256) {
      int rr = item >> 4, f4 = item & 15;
      *(float4*)&Ash[rr][f4 * 4] =
          ((const float4*)G)[(size_t)(d0 + rr) * 256 + (bi >> 2) + f4];
      *(float4*)&Bsh[rr][f4 * 4] =
          ((const float4*)G)[(size_t)(d0 + rr) * 256 + (bj >> 2) + f4];
    }
    __syncthreads();
    for (int dd = 0; dd < 64; dd++) {
      float av[4], bv[4];
      #pragma unroll
      for (int u = 0; u < 4; u++) av[u] = Ash[dd][a0 + u];
      #pragma unroll
      for (int u = 0; u < 4; u++) bv[u] = Bsh[dd][b0 + u];
      #pragma unroll
      for (int x = 0; x < 4; x++)
        #pragma unroll
        for (int y = 0; y < 4; y++) acc[x][y] += av[x] * bv[y];
    }
  }
  #pragma unroll
  for (int x = 0; x < 4; x++) {
    float4 v = make_float4(acc[x][0], acc[x][1], acc[x][2], acc[x][3]);
    ((float4*)G2)[(size_t)(bi + a0 + x) * 256 + ((bj + b0) >> 2)] = v;
  }
}

// ---------------------------------------------------------------------------
// fallback: initS fused with cut0 (block 0 scans diag(G), blocks 1.. init S).
__global__ void k_initScut(float* __restrict__ S, const float* __restrict__ G,
                           double* __restrict__ scal)
{
  int b = blockIdx.x;
  int t = threadIdx.x;
  if (b == 0) {
    __shared__ float red[256];
    float m = 0.f;
    for (int p = t; p < NB; p += 256) m = fmaxf(m, G[(size_t)p * NB + p]);
    red[t] = m;
    __syncthreads();
    for (int s = 128; s; s >>= 1) {
      if (t < s) red[t] = fmaxf(red[t], red[t + s]);
      __syncthreads();
    }
    if (t == 0) {
      double c = 0.9 * (double)red[0];
      scal[0] = c;
      scal[1] = c * c;
    }
    return;
  }
  int idx = (b - 1) * 256 + t;
  if (idx < NB * BSUB) {
    unsigned u = (unsigned)(idx + 1) * 2654435761u;
    u ^= u >> 16; u *= 2246822519u; u ^= u >> 13; u *= 3266489917u; u ^= u >> 16;
    S[idx] = ((float)u * (1.f / 4294967296.f)) - 0.5f;
  }
}

// ---------------------------------------------------------------------------
// Fused A@Z with split-K + in-kernel combine (fire-and-forget). A is G or G2.
// R9: split-K deepened to 16 (K=64 per block, single staging+compute pass);
// halves the per-step serial critical path of the Chebyshev chain.
__global__ __launch_bounds__(256) void k_gzfused(const float* __restrict__ G,
    const float* __restrict__ Z, const float* __restrict__ Zp,
    float* __restrict__ P, float* __restrict__ out, int* __restrict__ cnt,
    const double* __restrict__ cptr, float s1, float s2, float s3)
{
  __shared__ float Gs[32][68];
  __shared__ float Zs[64][84];
  __shared__ int lastf;
  int t = threadIdx.x;
  int r0b = blockIdx.x;
  int r0 = r0b * 32;
  int kz = blockIdx.y;
  int cg_ = t & 15, rg = t >> 4;
  float acc0[5] = {}, acc1[5] = {};
  int k0 = kz * 64;
  {
    #pragma unroll
    for (int s = 0; s < 2; s++) {
      int item = t + s * 256;
      int rr = item >> 4, f4 = item & 15;
      float4 g = ((const float4*)G)[(size_t)(r0 + rr) * 256 + (k0 >> 2) + f4];
      *(float4*)&Gs[rr][f4 * 4] = g;
    }
    #pragma unroll
    for (int s = 0; s < 5; s++) {
      int item = t + s * 256;
      int rr = item / 20, f4 = item % 20;
      float4 z = ((const float4*)Z)[(size_t)(k0 + rr) * 20 + f4];
      *(float4*)&Zs[rr][f4 * 4] = z;
    }
    __syncthreads();
    for (int kk = 0; kk < 64; kk++) {
      float g0 = Gs[rg * 2 + 0][kk];
      float g1 = Gs[rg * 2 + 1][kk];
      float z[5];
      #pragma unroll
      for (int m = 0; m < 5; m++) z[m] = Zs[kk][cg_ * 5 + m];
      #pragma unroll
      for (int m = 0; m < 5; m++) { acc0[m] += g0 * z[m]; acc1[m] += g1 * z[m]; }
    }
  }
  size_t base = (size_t)kz * (NB * BSUB) + (size_t)(r0 + rg * 2) * BSUB + cg_ * 5;
  #pragma unroll
  for (int m = 0; m < 5; m++) P[base + m] = acc0[m];
  #pragma unroll
  for (int m = 0; m < 5; m++) P[base + BSUB + m] = acc1[m];
  __threadfence();
  __syncthreads();
  if (t == 0) {
    int old = atomicAdd(&cnt[r0b], 1);
    lastf = (old == (KSPLIT - 1)) ? 1 : 0;
  }
  __syncthreads();
  if (!lastf) return;
  __threadfence();
  float coef = s1;
  if (cptr) coef = s1 * (float)(2.0 / cptr[0]);
  const float4* P4 = (const float4*)P;
  for (int idx = t; idx < 640; idx += 256) {
    size_t o4 = (size_t)r0 * 20 + idx;
    float4 a = P4[o4];
    #pragma unroll
    for (int u = 1; u < KSPLIT; u++) {
      float4 b = P4[(size_t)u * 20480 + o4];
      a.x += b.x; a.y += b.y; a.z += b.z; a.w += b.w;
    }
    float4 z = ((const float4*)Z)[o4];
    float4 o;
    o.x = coef * a.x + s2 * z.x;
    o.y = coef * a.y + s2 * z.y;
    o.z = coef * a.z + s2 * z.z;
    o.w = coef * a.w + s2 * z.w;
    if (s3 != 0.f) {
      float4 zp = ((const float4*)Zp)[o4];
      o.x += s3 * zp.x; o.y += s3 * zp.y; o.z += s3 * zp.z; o.w += s3 * zp.w;
    }
    ((float4*)out)[o4] = o;
  }
  __syncthreads();
  if (t == 0) cnt[r0b] = 0;
}

// ---------------------------------------------------------------------------
// fused X^T Y (16 blocks, partials in CP) + Cholesky/inverse run inline
// by the LAST finisher block.
__global__ __launch_bounds__(512) void k_xtychol(const float* __restrict__ Sa,
    const float* __restrict__ Sb, double* __restrict__ CP,
    float* __restrict__ Rinv, int* __restrict__ cnt)
{
  __shared__ float Xsh[64][BSUB + 1];
  __shared__ float Ysh[64][BSUB + 1];
  __shared__ int lastf;
  int t = threadIdx.x;
  int i0 = blockIdx.x * 64;
  for (int idx = t; idx < 64 * BSUB; idx += 512) {
    int r = idx / BSUB, c = idx % BSUB;
    Xsh[r][c] = Sa[(size_t)(i0 + r) * BSUB + c];
    Ysh[r][c] = Sb[(size_t)(i0 + r) * BSUB + c];
  }
  __syncthreads();
  if (t < 256) {
    int a0 = (t & 15) * 5, b0 = (t >> 4) * 5;
    double acc[5][5] = {};
    for (int dd = 0; dd < 64; dd++) {
      float av[5], bv[5];
      #pragma unroll
      for (int u = 0; u < 5; u++) av[u] = Xsh[dd][a0 + u];
      #pragma unroll
      for (int u = 0; u < 5; u++) bv[u] = Ysh[dd][b0 + u];
      #pragma unroll
      for (int x = 0; x < 5; x++)
        #pragma unroll
        for (int y = 0; y < 5; y++) acc[x][y] += (double)av[x] * (double)bv[y];
    }
    double* outp = CP + (size_t)blockIdx.x * (BSUB * BSUB);
    #pragma unroll
    for (int x = 0; x < 5; x++)
      #pragma unroll
      for (int y = 0; y < 5; y++)
        outp[(size_t)(a0 + x) * BSUB + (b0 + y)] = acc[x][y];
  }
  __threadfence();
  __syncthreads();
  if (t == 0) lastf = (atomicAdd(&cnt[0], 1) == 15) ? 1 : 0;
  __syncthreads();
  if (!lastf) return;
  if (t == 0) cnt[0] = 0;
  __threadfence();
  // ---- cholinv body (512 threads) ----
  __shared__ double R[BSUB][BSUB + 1];
  __shared__ double rownew[2][BSUB];
  __shared__ double dinv[BSUB];
  __shared__ float Xi[BSUB][BSUB + 1];
  for (int idx = t; idx < BSUB * BSUB; idx += 512) {
    double s = 0.0;
    #pragma unroll
    for (int b = 0; b < 16; b++) s += CP[(size_t)b * (BSUB * BSUB) + idx];
    R[idx / BSUB][idx % BSUB] = s;
  }
  __syncthreads();
  double flr0 = 1e-30 * (fabs(R[0][0]) + 1e-280);
  int prevrow = -1;
  int pb = 0;
  int k = 0;
  while (k < BSUB - 1) {
    int nrem = BSUB - 1 - k;
    int total = (nrem * (nrem + 1)) >> 1;
    int cplen = (prevrow >= 0) ? (BSUB - prevrow) : 0;
    double piv = R[k][k];
    if (piv < flr0) piv = flr0;
    double rp = 1.0 / piv;
    bool pair = (k + 1 < BSUB - 1);
    if (pair) {
      double dk1 = R[k][k + 1];
      double p1 = R[k + 1][k + 1] - dk1 * dk1 * rp;
      if (p1 < flr0) p1 = flr0;
      double rp1 = 1.0 / p1;
      for (int idx = t; idx < total + cplen; idx += 512) {
        if (idx < total) {
          float nf = 2.f * (float)nrem + 1.f;
          int a = (int)((nf - sqrtf(nf * nf - 8.f * (float)idx)) * 0.5f);
          while (a > 0 && a * nrem - ((a * (a - 1)) >> 1) > idx) a--;
          while ((a + 1) * nrem - (((a + 1) * a) >> 1) <= idx) a++;
          int off = idx - (a * nrem - ((a * (a - 1)) >> 1));
          int i2 = k + 1 + a, j2 = i2 + off;
          if (a == 0) {
            rownew[pb][j2] = R[k + 1][j2] - dk1 * R[k][j2] * rp;
          } else {
            double v = R[i2][j2] - R[k][i2] * R[k][j2] * rp;
            double R1i = R[k + 1][i2] - dk1 * R[k][i2] * rp;
            double R1j = R[k + 1][j2] - dk1 * R[k][j2] * rp;
            v -= R1i * R1j * rp1;
            R[i2][j2] = v;
          }
        } else {
          int j = prevrow + (idx - total);
          R[prevrow][j] = rownew[pb ^ 1][j];
        }
      }
      __syncthreads();
      prevrow = k + 1; pb ^= 1; k += 2;
    } else {
      for (int idx = t; idx < total + cplen; idx += 512) {
        if (idx < total) {
          float nf = 2.f * (float)nrem + 1.f;
          int a = (int)((nf - sqrtf(nf * nf - 8.f * (float)idx)) * 0.5f);
          while (a > 0 && a * nrem - ((a * (a - 1)) >> 1) > idx) a--;
          while ((a + 1) * nrem - (((a + 1) * a) >> 1) <= idx) a++;
          int off = idx - (a * nrem - ((a * (a - 1)) >> 1));
          int i2 = k + 1 + a, j2 = i2 + off;
          R[i2][j2] -= R[k][i2] * R[k][j2] * rp;
        } else {
          int j = prevrow + (idx - total);
          R[prevrow][j] = rownew[pb ^ 1][j];
        }
      }
      __syncthreads();
      prevrow = -1; k += 1;
    }
  }
  if (prevrow >= 0) {
    for (int j = prevrow + t; j < BSUB; j += 512) R[prevrow][j] = rownew[pb ^ 1][j];
    __syncthreads();
  }
  if (t < BSUB) {
    double piv = R[t][t];
    if (piv < flr0) piv = flr0;
    dinv[t] = 1.0 / sqrt(piv);
  }
  __syncthreads();
  for (int idx = t; idx < BSUB * BSUB; idx += 512) {
    int kk = idx / BSUB, j = idx % BSUB;
    if (j > kk) R[kk][j] *= dinv[kk];
  }
  __syncthreads();
  if (t < BSUB) R[t][t] = 1.0 / dinv[t];
  __syncthreads();
  if (t < BSUB) {
    int j = t;
    Xi[j][j] = (float)dinv[j];
    for (int i = j - 1; i >= 0; i--) {
      double s = 0.0;
      for (int k2 = i + 1; k2 <= j; k2++) s += R[i][k2] * (double)Xi[k2][j];
      Xi[i][j] = (float)(-s * dinv[i]);
    }
    for (int i = j + 1; i < BSUB; i++) Xi[i][j] = 0.f;
  }
  __syncthreads();
  for (int idx = t; idx < BSUB * BSUB; idx += 512)
    Rinv[idx] = Xi[idx / BSUB][idx % BSUB];
}

// out = S @ Rinv   (1024x80 * 80x80)
__global__ __launch_bounds__(256) void k_gemmSR(const float* __restrict__ S,
    const float* __restrict__ Rinv, float* __restrict__ out)
{
  __shared__ float Rsh[BSUB][84];
  int t = threadIdx.x;
  for (int idx = t; idx < BSUB * BSUB; idx += 256)
    Rsh[idx / BSUB][idx % BSUB] = Rinv[idx];
  __syncthreads();
  int r0 = blockIdx.x * 32;
  int r = t >> 3, c0 = (t & 7) * 10;
  float acc[10] = {};
  const float* srow = &S[(size_t)(r0 + r) * BSUB];
  for (int k = 0; k < BSUB; k++) {
    float s = srow[k];
    #pragma unroll
    for (int m = 0; m < 10; m++) acc[m] += s * Rsh[k][c0 + m];
  }
  #pragma unroll
  for (int m = 0; m < 10; m++) out[(size_t)(r0 + r) * BSUB + c0 + m] = acc[m];
}

// ---------------------------------------------------------------------------
// fused X^T Y (16 blocks) + 80x80 Jacobi run inline by the last finisher.
__global__ __launch_bounds__(1024) void k_xtyjac(const float* __restrict__ Sa,
    const float* __restrict__ Sb, double* __restrict__ CP,
    float* __restrict__ Uout, int* __restrict__ perm,
    double* __restrict__ cutout, int sweeps, int withU, int* __restrict__ cnt)
{
  __shared__ float Xsh[64][BSUB + 1];
  __shared__ float Ysh[64][BSUB + 1];
  __shared__ int lastf;
  int t = threadIdx.x;
  int i0 = blockIdx.x * 64;
  for (int idx = t; idx < 64 * BSUB; idx += 1024) {
    int r = idx / BSUB, c = idx % BSUB;
    Xsh[r][c] = Sa[(size_t)(i0 + r) * BSUB + c];
    Ysh[r][c] = Sb[(size_t)(i0 + r) * BSUB + c];
  }
  __syncthreads();
  if (t < 256) {
    int a0 = (t & 15) * 5, b0 = (t >> 4) * 5;
    double acc[5][5] = {};
    for (int dd = 0; dd < 64; dd++) {
      float av[5], bv[5];
      #pragma unroll
      for (int u = 0; u < 5; u++) av[u] = Xsh[dd][a0 + u];
      #pragma unroll
      for (int u = 0; u < 5; u++) bv[u] = Ysh[dd][b0 + u];
      #pragma unroll
      for (int x = 0; x < 5; x++)
        #pragma unroll
        for (int y = 0; y < 5; y++) acc[x][y] += (double)av[x] * (double)bv[y];
    }
    double* outp = CP + (size_t)blockIdx.x * (BSUB * BSUB);
    #pragma unroll
    for (int x = 0; x < 5; x++)
      #pragma unroll
      for (int y = 0; y < 5; y++)
        outp[(size_t)(a0 + x) * BSUB + (b0 + y)] = acc[x][y];
  }
  __threadfence();
  __syncthreads();
  if (t == 0) lastf = (atomicAdd(&cnt[0], 1) == 15) ? 1 : 0;
  __syncthreads();
  if (!lastf) return;
  if (t == 0) cnt[0] = 0;
  __threadfence();
  // ---- jacobi body (1024 threads) ----
  __shared__ float Mb[2][BSUB][BSUB + 1];
  __shared__ float Ut[BSUB][BSUB];
  __shared__ float4 rot[2][NPAIR];
  __shared__ float th[BSUB];
  __shared__ int id[BSUB];
  for (int idx = t; idx < BSUB * BSUB; idx += 1024) {
    double s = 0.0;
    #pragma unroll
    for (int b = 0; b < 16; b++) s += CP[(size_t)b * (BSUB * BSUB) + idx];
    Mb[1][idx / BSUB][idx % BSUB] = (float)s;
    if (withU) Ut[idx / BSUB][idx % BSUB] = ((idx / BSUB) == (idx % BSUB)) ? 1.f : 0.f;
  }
  int pr0 = t / 40, j0 = t - pr0 * 40;
  int pr1 = -1, j1 = 0;
  {
    int i1 = t + 1024;
    if (i1 < 1600) { pr1 = i1 / 40; j1 = i1 - pr1 * 40; }
  }
  int upr0 = -1, um0 = 0, upr1 = -1, um1 = 0;
  if (t >= 40) {
    int u0 = t - 40;              upr0 = u0 / 40; um0 = u0 - upr0 * 40;
    int u1 = t - 40 + 984;
    if (u1 < 1600) { upr1 = u1 / 40; um1 = u1 - upr1 * 40; }
  }
  int rp_ = 0, rq_ = 0;
  if (t < 40) {
    rp_ = (t == 0) ? 0 : 1 + (t - 1) % 79;
    rq_ = 1 + (78 - t) % 79;
  }
  __syncthreads();
  for (int idx = t; idx < BSUB * BSUB; idx += 1024) {
    int i2 = idx / BSUB, j2 = idx % BSUB;
    Mb[0][i2][j2] = 0.5f * (Mb[1][i2][j2] + Mb[1][j2][i2]);
  }
  __syncthreads();
  int nrounds = sweeps * (BSUB - 1);
  int mcur = 0;
  for (int it = 0; it < nrounds; it++) {
    int pb = it & 1;
    float (*Mc)[BSUB + 1] = Mb[mcur];
    float (*Mn)[BSUB + 1] = Mb[mcur ^ 1];
    if (t < 40) {
      int p = rp_, q = rq_;
      if (p > q) { int tmp = p; p = q; q = tmp; }
      float apq = Mc[p][q];
      float c = 1.f, s = 0.f;
      if (fabsf(apq) > 1e-28f) {
        float tau = (Mc[q][q] - Mc[p][p]) / (2.f * apq);
        float tt = copysignf(1.f, tau) / (fabsf(tau) + sqrtf(1.f + tau * tau));
        c = rsqrtf(1.f + tt * tt);
        s = tt * c;
      }
      rot[pb][t] = make_float4(c, s, __int_as_float(p), __int_as_float(q));
      if (t > 0) rp_ = (rp_ == 79) ? 1 : rp_ + 1;
      rq_ = (rq_ == 79) ? 1 : rq_ + 1;
    } else if (withU && it > 0) {
      int ob = pb ^ 1;
      {
        float4 R0 = rot[ob][upr0];
        int p = __float_as_int(R0.z), q = __float_as_int(R0.w);
        float c = R0.x, s = R0.y;
        float2 up = *(float2*)&Ut[p][2 * um0];
        float2 uq = *(float2*)&Ut[q][2 * um0];
        float2 np, nq;
        np.x = c * up.x - s * uq.x;  np.y = c * up.y - s * uq.y;
        nq.x = s * up.x + c * uq.x;  nq.y = s * up.y + c * uq.y;
        *(float2*)&Ut[p][2 * um0] = np;
        *(float2*)&Ut[q][2 * um0] = nq;
      }
      if (upr1 >= 0) {
        float4 R1 = rot[ob][upr1];
        int p = __float_as_int(R1.z), q = __float_as_int(R1.w);
        float c = R1.x, s = R1.y;
        float2 up = *(float2*)&Ut[p][2 * um1];
        float2 uq = *(float2*)&Ut[q][2 * um1];
        float2 np, nq;
        np.x = c * up.x - s * uq.x;  np.y = c * up.y - s * uq.y;
        nq.x = s * up.x + c * uq.x;  nq.y = s * up.y + c * uq.y;
        *(float2*)&Ut[p][2 * um1] = np;
        *(float2*)&Ut[q][2 * um1] = nq;
      }
    }
    __syncthreads();
    {
      float4 Rp = rot[pb][pr0];
      float4 Rj = rot[pb][j0];
      int p = __float_as_int(Rp.z), q = __float_as_int(Rp.w);
      float c = Rp.x, s = Rp.y;
      int k = __float_as_int(Rj.z), k2 = __float_as_int(Rj.w);
      float cj = Rj.x, sj = Rj.y;
      float mpk = Mc[p][k],  mqk = Mc[q][k];
      float mpk2 = Mc[p][k2], mqk2 = Mc[q][k2];
      float rpk  = c * mpk  - s * mqk;
      float rqk  = s * mpk  + c * mqk;
      float rpk2 = c * mpk2 - s * mqk2;
      float rqk2 = s * mpk2 + c * mqk2;
      Mn[p][k]  = cj * rpk - sj * rpk2;
      Mn[q][k]  = cj * rqk - sj * rqk2;
      Mn[p][k2] = sj * rpk + cj * rpk2;
      Mn[q][k2] = sj * rqk + cj * rqk2;
    }
    if (pr1 >= 0) {
      float4 Rp = rot[pb][pr1];
      float4 Rj = rot[pb][j1];
      int p = __float_as_int(Rp.z), q = __float_as_int(Rp.w);
      float c = Rp.x, s = Rp.y;
      int k = __float_as_int(Rj.z), k2 = __float_as_int(Rj.w);
      float cj = Rj.x, sj = Rj.y;
      float mpk = Mc[p][k],  mqk = Mc[q][k];
      float mpk2 = Mc[p][k2], mqk2 = Mc[q][k2];
      float rpk  = c * mpk  - s * mqk;
      float rqk  = s * mpk  + c * mqk;
      float rpk2 = c * mpk2 - s * mqk2;
      float rqk2 = s * mpk2 + c * mqk2;
      Mn[p][k]  = cj * rpk - sj * rpk2;
      Mn[q][k]  = cj * rqk - sj * rqk2;
      Mn[p][k2] = sj * rpk + cj * rpk2;
      Mn[q][k2] = sj * rqk + cj * rqk2;
    }
    __syncthreads();
    mcur ^= 1;
  }
  if (withU) {
    int ob = (nrounds - 1) & 1;
    {
      float4 R0 = rot[ob][pr0];
      int p = __float_as_int(R0.z), q = __float_as_int(R0.w);
      float c = R0.x, s = R0.y;
      float2 up = *(float2*)&Ut[p][2 * j0];
      float2 uq = *(float2*)&Ut[q][2 * j0];
      float2 np, nq;
      np.x = c * up.x - s * uq.x;  np.y = c * up.y - s * uq.y;
      nq.x = s * up.x + c * uq.x;  nq.y = s * up.y + c * uq.y;
      *(float2*)&Ut[p][2 * j0] = np;
      *(float2*)&Ut[q][2 * j0] = nq;
    }
    if (pr1 >= 0) {
      float4 R1 = rot[ob][pr1];
      int p = __float_as_int(R1.z), q = __float_as_int(R1.w);
      float c = R1.x, s = R1.y;
      float2 up = *(float2*)&Ut[p][2 * j1];
      float2 uq = *(float2*)&Ut[q][2 * j1];
      float2 np, nq;
      np.x = c * up.x - s * uq.x;  np.y = c * up.y - s * uq.y;
      nq.x = s * up.x + c * uq.x;  nq.y = s * up.y + c * uq.y;
      *(float2*)&Ut[p][2 * j1] = np;
      *(float2*)&Ut[q][2 * j1] = nq;
    }
    __syncthreads();
  }
  float (*Mf)[BSUB + 1] = Mb[mcur];
  if (t < BSUB) { th[t] = Mf[t][t]; id[t] = t; }
  __syncthreads();
  if (t == 0) {
    for (int a = 1; a < BSUB; a++) {
      float v = th[a]; int ii = id[a]; int b = a - 1;
      while (b >= 0 && th[b] < v) { th[b + 1] = th[b]; id[b + 1] = id[b]; b--; }
      th[b + 1] = v; id[b + 1] = ii;
    }
    double cut = (double)th[BSUB - 1];
    double lo = 0.02 * (double)th[0];
    if (cut < lo) cut = lo;
    double hi = 0.98 * (double)th[63];
    if (cut > hi) cut = hi;
    cutout[0] = cut;
    cutout[1] = cut * cut;
  }
  __syncthreads();
  if (t < BSUB) perm[t] = id[t];
  if (withU)
    for (int idx = t; idx < BSUB * BSUB; idx += 1024) {
      int k = idx / BSUB, p = idx % BSUB;
      Uout[idx] = Ut[p][k];
    }
}

// out[:, c] = S @ U[:, perm[c]], c < 64
__global__ __launch_bounds__(256) void k_compose(const float* __restrict__ S,
    const float* __restrict__ U, const int* __restrict__ perm,
    float* __restrict__ out)
{
  __shared__ float Ush[BSUB][65];
  int t = threadIdx.x;
  for (int idx = t; idx < BSUB * 64; idx += 256) {
    int jj = idx >> 6, c = idx & 63;
    Ush[jj][c] = U[jj * BSUB + perm[c]];
  }
  __syncthreads();
  int r0 = blockIdx.x * 64;
  for (int oidx = t; oidx < 64 * 64; oidx += 256) {
    int r = oidx >> 6, c = oidx & 63;
    float acc = 0.f;
    const float* srow = &S[(size_t)(r0 + r) * BSUB];
    #pragma unroll 8
    for (int j = 0; j < BSUB; j++) acc += srow[j] * Ush[j][c];
    out[(size_t)(r0 + r) * 64 + c] = acc;
  }
}

// ---------------------------------------------------------------------------
// fused: proj[d] = (1/16) * neigh_d @ Vtop, then hout = relu(proj @ W^T + b)
// When Xmat != nullptr, neighbor rows are read LINEARLY from X.
__global__ __launch_bounds__(256) void k_projlin(const float* __restrict__ hl,
    const int* __restrict__ src, const float* __restrict__ Vtop,
    const float* __restrict__ W, const float* __restrict__ bias,
    float* __restrict__ hout, const float* __restrict__ Xmat)
{
  __shared__ float Vsh[64][68];
  __shared__ float Hsh[64][68];
  __shared__ float Psh[64][68];
  int t = threadIdx.x;
  int d0 = blockIdx.x * 64;
  int dd = t & 63, pg = t >> 6;
  float acc[16] = {};
  for (int k = 0; k < 16; k++) {
    __syncthreads();
    for (int item = t; item < 1024; item += 256) {
      int rr = item >> 4, f4 = item & 15;
      *(float4*)&Vsh[rr][f4 * 4] = ((const float4*)Vtop)[(size_t)(k * 64 + rr) * 16 + f4];
      int d = d0 + rr;
      float4 v = make_float4(0.f, 0.f, 0.f, 0.f);
      if (d < NNODES) {
        if (Xmat) {
          v = ((const float4*)Xmat)[(size_t)d * 256 + k * 16 + f4];
        } else {
          int row = (k < EPN) ? src[d * EPN + k] : d;
          v = ((const float4*)hl)[(size_t)row * 16 + f4];
        }
      }
      *(float4*)&Hsh[rr][f4 * 4] = v;
    }
    __syncthreads();
    for (int j = 0; j < 64; j++) {
      float h = Hsh[dd][j];
      #pragma unroll
      for (int m = 0; m < 16; m++) acc[m] += h * Vsh[j][pg * 16 + m];
    }
  }
  __syncthreads();
  #pragma unroll
  for (int m = 0; m < 16; m++) Psh[dd][pg * 16 + m] = acc[m] * (1.f / 16.f);
  for (int item = t; item < 1024; item += 256) {
    int rr = item >> 4, f4 = item & 15;
    *(float4*)&Vsh[rr][f4 * 4] = ((const float4*)W)[(size_t)rr * 16 + f4];
  }
  __syncthreads();
  if (d0 + dd < NNODES) {
    #pragma unroll
    for (int m = 0; m < 16; m++) {
      int o = pg * 16 + m;
      float a = bias[o];
      for (int j = 0; j < 64; j++) a += Psh[dd][j] * Vsh[o][j];
      hout[(size_t)(d0 + dd) * 64 + o] = fmaxf(a, 0.f);
    }
  }
}

__global__ void k_logsoftmax(const float* __restrict__ logits, float* __restrict__ out)
{
  int n = blockIdx.x * 256 + threadIdx.x;
  if (n >= NNODES) return;
  float v[NCLS];
  float mx = -1e30f;
  #pragma unroll
  for (int c = 0; c < NCLS; c++) { v[c] = logits[(size_t)n * NCLS + c]; mx = fmaxf(mx, v[c]); }
  float se = 0.f;
  #pragma unroll
  for (int c = 0; c < NCLS; c++) se += expf(v[c] - mx);
  float lse = mx + logf(se);
  #pragma unroll
  for (int c = 0; c < NCLS; c++) out[(size_t)n * NCLS + c] = v[c] - lse;
}

// ===========================================================================
extern "C" void kernel_launch(void* const* d_in, const int* in_sizes, int n_in,
                              void* d_out, int out_size, void* d_ws, size_t ws_size,
                              hipStream_t stream)
{
  (void)in_sizes; (void)n_in; (void)out_size;
  const float* x = (const float*)d_in[0];
  const int* src = (const int*)d_in[1];
  const float* Wl[3] = { (const float*)d_in[2], (const float*)d_in[4], (const float*)d_in[6] };
  const float* bl[3] = { (const float*)d_in[3], (const float*)d_in[5], (const float*)d_in[7] };
  const float* Wfc = (const float*)d_in[8];
  const float* bfc = (const float*)d_in[9];
  float* outp = (float*)d_out;

  char* w = (char*)d_ws;
  auto alloc = [&](size_t bytes) -> char* {
    char* p = w; w += (bytes + 255) & ~(size_t)255; return p;
  };
  float* hA   = (float*)alloc((size_t)NNODES * 64 * 4);
  float* hB   = (float*)alloc((size_t)NNODES * 64 * 4);
  float* hl   = (float*)alloc((size_t)NNODES * 64 * 4);
  float* T    = (float*)alloc((size_t)NB * NB * 4);
  float* G    = (float*)alloc((size_t)NB * NB * 4);
  float* G2   = (float*)alloc((size_t)NB * NB * 4);
  float* mus  = (float*)alloc(16 * 64 * 4);
  float* Zb[6];
  for (int i = 0; i < 6; i++) Zb[i] = (float*)alloc((size_t)NB * BSUB * 4);
  float* P     = (float*)alloc((size_t)KSPLIT * NB * BSUB * 4);
  int* cnt     = (int*)alloc(64 * 4);
  double* CP   = (double*)alloc((size_t)16 * BSUB * BSUB * 8);   // 16 f64 partials
  float* Rinv  = (float*)alloc(BSUB * BSUB * 4);
  float* U     = (float*)alloc(BSUB * BSUB * 4);
  int* perm    = (int*)alloc(BSUB * 4);
  float* Vtop  = (float*)alloc((size_t)NB * 64 * 4);
  double* scal = (double*)alloc(16 * 8);
  // fast-gram extras (used only when workspace permits).
  float* X      = (float*)alloc((size_t)NNODES * NB * 4);                // ~82 MB
  float* TP     = (float*)alloc((size_t)16 * (size_t)NB * NB * 4);       // ~67 MB
  size_t used16 = (size_t)(w - (char*)d_ws);
  (void)alloc((size_t)4 * (size_t)NB * NB * 4);                          // +17 MB
  size_t used20 = (size_t)(w - (char*)d_ws);
  int fastg = (used16 <= ws_size) ? 1 : 0;
  int NS    = (used20 <= ws_size) ? 20 : 16;

  const int GRID_ROWS = (NNODES + 63) / 64;   // 313

  hipMemsetAsync(cnt, 0, 64 * 4, stream);     // combine counters (self-resetting)

  int cur = 0;
  auto gemmGZ = [&](const float* A, const float* Z, const float* Zp, float* o,
                    const double* cptr, float s1, float s2, float s3) {
    hipLaunchKernelGGL(k_gzfused, dim3(32, KSPLIT), dim3(256), 0, stream,
                       A, Z, Zp, P, o, cnt, cptr, s1, s2, s3);
  };
  auto chunk2 = [&](int deg, const double* cptr) {
    int a = (cur + 1) % 6, b = (cur + 2) % 6;
    float* bufs[3] = { Zb[cur], Zb[a], Zb[b] };
    int ip = 0, ic = 0, io = 1;
    for (int s = 0; s < deg; s++) {
      if (s == 0)
        gemmGZ(G2, bufs[ic], nullptr, bufs[io], cptr, 1.f, -1.f, 0.f);
      else
        gemmGZ(G2, bufs[ic], bufs[ip], bufs[io], cptr, 2.f, -2.f, -1.f);
      if (s == 0) { ip = 0; ic = 1; io = 2; }
      else { int tmp = ip; ip = ic; ic = io; io = tmp; }
    }
    int sel = (deg - 1) % 3;
    cur = (sel == 0) ? a : (sel == 1) ? b : cur;
  };
  auto cholqr = [&]() {
    hipLaunchKernelGGL(k_xtychol, dim3(16), dim3(512), 0, stream,
                       Zb[cur], Zb[cur], CP, Rinv, cnt + 32);
    int o = (cur + 1) % 6;
    hipLaunchKernelGGL(k_gemmSR, dim3(32), dim3(256), 0, stream, Zb[cur], Rinv, Zb[o]);
    cur = o;
  };
  auto rrmid = [&](double* cutp) {
    int y = (cur + 1) % 6;
    gemmGZ(G, Zb[cur], nullptr, Zb[y], nullptr, 1.f, 0.f, 0.f);   // Y = G S
    hipLaunchKernelGGL(k_xtyjac, dim3(16), dim3(1024), 0, stream,
                       Zb[cur], Zb[y], CP, U, perm, cutp, 2, 0, cnt + 33);
  };
  auto rrfinal = [&](double* cutp) {
    int y = (cur + 1) % 6;
    gemmGZ(G, Zb[cur], nullptr, Zb[y], nullptr, 1.f, 0.f, 0.f);   // Y = G S
    hipLaunchKernelGGL(k_xtyjac, dim3(16), dim3(1024), 0, stream,
                       Zb[cur], Zb[y], CP, U, perm, cutp, 5, 1, cnt + 33);
    hipLaunchKernelGGL(k_compose, dim3(16), dim3(256), 0, stream,
                       Zb[cur], U, perm, Vtop);
  };

  const float* hin = x;
  float* hout = hA;
  for (int l = 0; l < 3; l++) {
    hipLaunchKernelGGL(k_linT, dim3(GRID_ROWS), dim3(256), 0, stream,
                       hin, Wl[l], (const float*)nullptr, hl, 64, 0);
    hipMemsetAsync(mus, 0, 16 * 64 * 4, stream);
    if (fastg) {
      hipLaunchKernelGGL(k_buildX, dim3(GRID_ROWS), dim3(256), 0, stream,
                         hl, src, X, mus);
      hipLaunchKernelGGL(k_syrkX, dim3(36 * NS), dim3(256), 0, stream,
                         X, TP, NNODES / NS, mus);
      hipLaunchKernelGGL(k_assembleG16, dim3(4096), dim3(256), 0, stream,
                         TP, G, NS, 1.f / 256.f,
                         (float*)nullptr, (const float*)nullptr, (double*)nullptr);
      // G2 = G^T G via the same SYRK (G symmetric; identical row layout).
      hipLaunchKernelGGL(k_syrkX, dim3(36 * 4), dim3(256), 0, stream,
                         G, TP, NB / 4, (const float*)nullptr);
      cur = 0;
      // assemble G2 + fold in cut0 (block 4096) and S-init (blocks 4097..)
      hipLaunchKernelGGL(k_assembleG16, dim3(4096 + 1 + 320), dim3(256), 0, stream,
                         TP, G2, 4, 1.f, Zb[cur], G, scal);
    } else {
      hipLaunchKernelGGL(k_meanslot, dim3(16, 8), dim3(256), 0, stream, hl, src, mus);
      hipMemsetAsync(T, 0, (size_t)NB * NB * 4, stream);
      hipLaunchKernelGGL(k_gram, dim3(136, 5), dim3(256), 0, stream, hl, src, mus, T);
      hipLaunchKernelGGL(k_assembleG, dim3(4096), dim3(256), 0, stream, T, G);
      hipLaunchKernelGGL(k_gemmG2, dim3(16, 16), dim3(256), 0, stream, G, G2);
      cur = 0;
      hipLaunchKernelGGL(k_initScut, dim3(1 + (NB * BSUB + 255) / 256), dim3(256), 0,
                         stream, Zb[cur], G, scal);
    }
    chunk2(6, &scal[1]); cholqr();          // T12 filter
    rrmid(&scal[2]);                        // writes scal[2]=cut, scal[3]=cut^2
    chunk2(7, &scal[3]); cholqr();          // T14
    chunk2(7, &scal[3]); cholqr();          // T14
    rrfinal(&scal[4]);
    hipLaunchKernelGGL(k_projlin, dim3(GRID_ROWS), dim3(256), 0, stream,
                       hl, src, Vtop, Wl[l], bl[l], hout,
                       fastg ? (const float*)X : (const float*)nullptr);
    hin = hout;
    hout = (hout == hA) ? hB : hA;
  }
  hipLaunchKernelGGL(k_linT, dim3(GRID_ROWS), dim3(256), 0, stream,
                     hin, Wfc, bfc, hl, NCLS, 0);
  hipLaunchKernelGGL(k_logsoftmax, dim3((NNODES + 255) / 256), dim3(256), 0, stream,
                     hl, outp);
}

// Round 10
// 8095.866 us; speedup vs baseline: 1.2243x; 1.2243x over previous
//
#include <hip/hip_runtime.h>
#include <cmath>

#define NNODES 20000
#define FD 64
#define EPN 15      // regular edges per node
#define NB 1024     // DEG * F
#define BSUB 80     // subspace width (top-64 + 16 buffer)
#define NCLS 16
#define NPAIR 40

// ---------------------------------------------------------------------------
// out[n][o] = relu?( sum_j X[n][j] * W[o][j] + bias[o] ), X: [N,64], W: [ncol,64]
__global__ __launch_bounds__(256) void k_linT(const float* __restrict__ X,
    const float* __restrict__ W, const float* __restrict__ bias,
    float* __restrict__ out, int ncol, int relu)
{
  __shared__ float Wsh[64][65];
  __shared__ float Xsh[64][65];
  int t = threadIdx.x;
  int r0 = blockIdx.x * 64;
  for (int idx = t; idx < ncol * 64; idx += 256) Wsh[idx >> 6][idx & 63] = W[idx];
  for (int idx = t; idx < 64 * 64; idx += 256) {
    int r = idx >> 6, c = idx & 63;
    Xsh[r][c] = (r0 + r < NNODES) ? X[(size_t)(r0 + r) * 64 + c] : 0.f;
  }
  __syncthreads();
  for (int idx = t; idx < 64 * ncol; idx += 256) {
    int r = idx / ncol, o = idx % ncol;
    float acc = 0.f;
    #pragma unroll
    for (int j = 0; j < 64; j++) acc += Xsh[r][j] * Wsh[o][j];
    if (bias) acc += bias[o];
    if (relu) acc = fmaxf(acc, 0.f);
    if (r0 + r < NNODES) out[(size_t)(r0 + r) * ncol + o] = acc;
  }
}

// ---------------------------------------------------------------------------
// fallback: mus from gathered hl (used only when X not materialized)
__global__ __launch_bounds__(256) void k_meanslot(const float* __restrict__ hl,
    const int* __restrict__ src, float* __restrict__ mus)
{
  int k = blockIdx.x;          // slot 0..15
  int part = blockIdx.y;       // 8 parts x 2500 nodes
  int t = threadIdx.x;
  int c = t & 63, sub = t >> 6;
  int d0 = part * 2500;
  float acc = 0.f;
  for (int d = d0 + sub; d < d0 + 2500; d += 4) {
    int row = (k < EPN) ? src[d * EPN + k] : d;
    acc += hl[(size_t)row * 64 + c];
  }
  __shared__ float red[4][64];
  red[sub][c] = acc;
  __syncthreads();
  if (t < 64) {
    float s = red[0][t] + red[1][t] + red[2][t] + red[3][t];
    atomicAdd(&mus[k * 64 + t], s * (1.f / 20000.f));
  }
}

// ---------------------------------------------------------------------------
// Materialize UNCENTERED X[d][k*64+f] = hl[row(d,k)][f]. R8: also accumulates
// the per-column partial sums into mus (LDS float atomics; one global
// atomicAdd per column per block) — removes the separate meanslot pass.
__global__ __launch_bounds__(256) void k_buildX(const float* __restrict__ hl,
    const int* __restrict__ src, float* __restrict__ X, float* __restrict__ mus)
{
  __shared__ float msum[1024];
  int t = threadIdx.x;
  for (int i = t; i < 1024; i += 256) msum[i] = 0.f;
  __syncthreads();
  int d0 = blockIdx.x * 64;
  for (int k = 0; k < 16; k++) {
    float4 acc = make_float4(0.f, 0.f, 0.f, 0.f);
    #pragma unroll
    for (int s = 0; s < 4; s++) {
      int item = t + s * 256;
      int rr = item >> 4, f4 = item & 15;
      int d = d0 + rr;
      if (d < NNODES) {
        int row = (k < EPN) ? src[d * EPN + k] : d;
        float4 v = ((const float4*)hl)[(size_t)row * 16 + f4];
        ((float4*)X)[(size_t)d * 256 + k * 16 + f4] = v;
        acc.x += v.x; acc.y += v.y; acc.z += v.z; acc.w += v.w;
      }
    }
    int base = k * 64 + (t & 15) * 4;
    atomicAdd(&msum[base + 0], acc.x);
    atomicAdd(&msum[base + 1], acc.y);
    atomicAdd(&msum[base + 2], acc.z);
    atomicAdd(&msum[base + 3], acc.w);
  }
  __syncthreads();
  for (int i = t; i < 1024; i += 256)
    if (msum[i] != 0.f) atomicAdd(&mus[i], msum[i] * (1.f / 20000.f));
}

// ---------------------------------------------------------------------------
// SYRK over rows of X (layout: [nrows][256 float4]): TP[kz] = upper 128x128
// tiles of (X - mu)^T (X - mu) over row-slice kz. 8x8 per-thread, conflict-
// free fragments (R3), register-prefetch (R4). mus==nullptr -> no centering
// (used for G2 = G^T G). R8: 1-D grid + bijective XCD-chunk swizzle so each
// XCD's co-resident blocks cover a contiguous (slice,tile) range — per-XCD
// L2 working set drops from ~all slices to ~2.5 (one slice's panels = 4 MB
// = one XCD L2). gridDim.x = 36*nslices, must be divisible by 8.
__global__ __launch_bounds__(256) void k_syrkX(const float* __restrict__ X,
    float* __restrict__ TP, int rows, const float* __restrict__ mus)
{
  __shared__ float As[32][128];
  __shared__ float Bs[32][128];
  __shared__ float muA[128], muB[128];
  int t = threadIdx.x;
  int nb = gridDim.x;
  int f = blockIdx.x;
  int orig = (f & 7) * (nb >> 3) + (f >> 3);   // XCD-chunk swizzle (bijective)
  int kzS = orig / 36;
  int pr = orig % 36;
  int I = 0, rem = pr;
  for (int ii = 0; ii < 8; ii++) {
    int cnt = 8 - ii;
    if (rem < cnt) { I = ii; break; }
    rem -= cnt;
  }
  int J = I + rem;
  if (t < 128) muA[t] = mus ? mus[I * 128 + t] : 0.f;
  else muB[t - 128] = mus ? mus[J * 128 + (t - 128)] : 0.f;
  __syncthreads();
  int d0 = kzS * rows;
  int d1 = d0 + rows;
  int a0 = (t & 15) * 4, b0 = (t >> 4) * 4;
  float4 pa[4], pb[4];
  auto LOADR = [&](int dc) {
    #pragma unroll
    for (int s = 0; s < 4; s++) {
      int idx = t + s * 256;
      int rr = idx >> 5, c4 = idx & 31;
      int d = dc + rr;
      float4 va = make_float4(0.f, 0.f, 0.f, 0.f), vb = va;
      if (d < d1) {
        va = ((const float4*)X)[(size_t)d * 256 + I * 32 + c4];
        vb = ((const float4*)X)[(size_t)d * 256 + J * 32 + c4];
        float4 ma = *(const float4*)&muA[c4 * 4];
        float4 mb = *(const float4*)&muB[c4 * 4];
        va.x -= ma.x; va.y -= ma.y; va.z -= ma.z; va.w -= ma.w;
        vb.x -= mb.x; vb.y -= mb.y; vb.z -= mb.z; vb.w -= mb.w;
      }
      pa[s] = va; pb[s] = vb;
    }
  };
  LOADR(d0);
  float acc[8][8] = {};
  for (int dc = d0; dc < d1; dc += 32) {
    __syncthreads();
    #pragma unroll
    for (int s = 0; s < 4; s++) {
      int idx = t + s * 256;
      int rr = idx >> 5, c4 = idx & 31;
      *(float4*)&As[rr][c4 * 4] = pa[s];
      *(float4*)&Bs[rr][c4 * 4] = pb[s];
    }
    __syncthreads();
    if (dc + 32 < d1) LOADR(dc + 32);
    for (int dd = 0; dd < 32; dd++) {
      float av[8], bv[8];
      *(float4*)&av[0] = *(const float4*)&As[dd][a0];
      *(float4*)&av[4] = *(const float4*)&As[dd][a0 + 64];
      *(float4*)&bv[0] = *(const float4*)&Bs[dd][b0];
      *(float4*)&bv[4] = *(const float4*)&Bs[dd][b0 + 64];
      #pragma unroll
      for (int x = 0; x < 8; x++)
        #pragma unroll
        for (int y = 0; y < 8; y++) acc[x][y] += av[x] * bv[y];
    }
  }
  float* Tout = TP + (size_t)kzS * ((size_t)NB * NB);
  #pragma unroll
  for (int x = 0; x < 8; x++) {
    int rowi = I * 128 + ((x < 4) ? (a0 + x) : (64 + a0 + x - 4));
    size_t base = (size_t)rowi * NB + J * 128;
    *(float4*)&Tout[base + b0]      = make_float4(acc[x][0], acc[x][1], acc[x][2], acc[x][3]);
    *(float4*)&Tout[base + 64 + b0] = make_float4(acc[x][4], acc[x][5], acc[x][6], acc[x][7]);
  }
}

// sum the ns split-K partials + symmetrize + scale. When Sinit != nullptr,
// blocks >= 4096 additionally run cut0 (block 4096) and the S hash-init.
__global__ __launch_bounds__(256) void k_assembleG16(const float* __restrict__ TP,
    float* __restrict__ G, int ns, float scale,
    float* __restrict__ Sinit, const float* __restrict__ Gd,
    double* __restrict__ scal)
{
  int b = blockIdx.x;
  int t = threadIdx.x;
  if (b >= 4096) {
    if (b == 4096) {
      __shared__ float red[256];
      float m = 0.f;
      for (int p = t; p < NB; p += 256) m = fmaxf(m, Gd[(size_t)p * NB + p]);
      red[t] = m;
      __syncthreads();
      for (int s = 128; s; s >>= 1) {
        if (t < s) red[t] = fmaxf(red[t], red[t + s]);
        __syncthreads();
      }
      if (t == 0) {
        double c = 0.9 * (double)red[0];
        scal[0] = c;
        scal[1] = c * c;
      }
    } else {
      int idx = (b - 4097) * 256 + t;
      if (idx < NB * BSUB) {
        unsigned u = (unsigned)(idx + 1) * 2654435761u;
        u ^= u >> 16; u *= 2246822519u; u ^= u >> 13; u *= 3266489917u; u ^= u >> 16;
        Sinit[idx] = ((float)u * (1.f / 4294967296.f)) - 0.5f;
      }
    }
    return;
  }
  size_t idx = (size_t)b * 256 + t;
  int p = (int)(idx >> 10), q = (int)(idx & 1023);
  int ti = p >> 6, tj = q >> 6;
  size_t e = (ti <= tj) ? idx : (((size_t)q << 10) | (size_t)p);
  float v = 0.f;
  for (int s2 = 0; s2 < ns; s2++) v += TP[(size_t)s2 * ((size_t)NB * NB) + e];
  G[idx] = v * scale;
}

// ---------------------------------------------------------------------------
// fallback gram path (used only if workspace too small for X/TP)
__global__ __launch_bounds__(256) void k_gram(const float* __restrict__ hl,
    const int* __restrict__ src, const float* __restrict__ mus,
    float* __restrict__ T)
{
  __shared__ float Ash[64][64];
  __shared__ float Bsh[64][64];
  __shared__ float muA[64], muB[64];
  int t = threadIdx.x;
  int pr = blockIdx.x, i = 0, rem = pr;
  for (int ii = 0; ii < 16; ii++) {
    int cnt = 16 - ii;
    if (rem < cnt) { i = ii; break; }
    rem -= cnt;
  }
  int j = i + rem;
  if (t < 64) muA[t] = mus[i * 64 + t];
  else if (t < 128) muB[t - 64] = mus[j * 64 + (t - 64)];
  float acc[4][4] = {};
  int a0 = (t & 15) * 4, b0 = (t >> 4) * 4;
  int d0 = blockIdx.y * 4000, d1 = d0 + 4000;
  for (int dc = d0; dc < d1; dc += 64) {
    __syncthreads();
    for (int item = t; item < 1024; item += 256) {
      int rr = item >> 4, f4 = item & 15;
      int d = dc + rr;
      float4 va = make_float4(0.f, 0.f, 0.f, 0.f);
      float4 vb = va;
      if (d < d1) {
        int ra = (i < EPN) ? src[d * EPN + i] : d;
        int rb = (j < EPN) ? src[d * EPN + j] : d;
        va = ((const float4*)hl)[(size_t)ra * 16 + f4];
        vb = ((const float4*)hl)[(size_t)rb * 16 + f4];
        int cb = f4 * 4;
        va.x -= muA[cb]; va.y -= muA[cb + 1]; va.z -= muA[cb + 2]; va.w -= muA[cb + 3];
        vb.x -= muB[cb]; vb.y -= muB[cb + 1]; vb.z -= muB[cb + 2]; vb.w -= muB[cb + 3];
      }
      ((float4*)&Ash[rr][0])[f4] = va;
      ((float4*)&Bsh[rr][0])[f4] = vb;
    }
    __syncthreads();
    for (int dd = 0; dd < 64; dd++) {
      float av[4], bv[4];
      #pragma unroll
      for (int u = 0; u < 4; u++) av[u] = Ash[dd][a0 + u];
      #pragma unroll
      for (int u = 0; u < 4; u++) bv[u] = Bsh[dd][b0 + u];
      #pragma unroll
      for (int x = 0; x < 4; x++)
        #pragma unroll
        for (int y = 0; y < 4; y++) acc[x][y] += av[x] * bv[y];
    }
  }
  #pragma unroll
  for (int x = 0; x < 4; x++)
    #pragma unroll
    for (int y = 0; y < 4; y++)
      atomicAdd(&T[(size_t)(i * 64 + a0 + x) * NB + (j * 64 + b0 + y)], acc[x][y]);
}

// ---------------------------------------------------------------------------
__global__ __launch_bounds__(256) void k_assembleG(const float* __restrict__ T,
    float* __restrict__ G)
{
  size_t idx = (size_t)blockIdx.x * 256 + threadIdx.x;
  int p = (int)(idx >> 10), q = (int)(idx & 1023);
  int ti = p >> 6, tj = q >> 6;
  float v = (ti <= tj) ? T[idx] : T[((size_t)q << 10) | (size_t)p];
  G[idx] = v * (1.f / 256.f);
}

// ---------------------------------------------------------------------------
// G2 = G @ G (fallback path only; fast path uses k_syrkX on G).
__global__ __launch_bounds__(256) void k_gemmG2(const float* __restrict__ G,
    float* __restrict__ G2)
{
  __shared__ float Ash[64][68];
  __shared__ float Bsh[64][68];
  int t = threadIdx.x;
  int bi = blockIdx.x * 64, bj = blockIdx.y * 64;
  int a0 = (t & 15) * 4, b0 = (t >> 4) * 4;
  float acc[4][4] = {};
  for (int d0 = 0; d0 < NB; d0 += 64) {
    __syncthreads();
    for (int item = t; item < 1024; item += 256) {
      int rr = item >> 4, f4 = item & 15;
      *(float4*)&Ash[rr][f4 * 4] =
          ((const float4*)G)[(size_t)(d0 + rr) * 256 + (bi >> 2) + f4];
      *(float4*)&Bsh[rr][f4 * 4] =
          ((const float4*)G)[(size_t)(d0 + rr) * 256 + (bj >> 2) + f4];
    }
    __syncthreads();
    for (int dd = 0; dd < 64; dd++) {
      float av[4], bv[4];
      #pragma unroll
      for (int u = 0; u < 4; u++) av[u] = Ash[dd][a0 + u];
      #pragma unroll
      for (int u = 0; u < 4; u++) bv[u] = Bsh[dd][b0 + u];
      #pragma unroll
      for (int x = 0; x < 4; x++)
        #pragma unroll
        for (int y = 0; y < 4; y++) acc[x][y] += av[x] * bv[y];
    }
  }
  #pragma unroll
  for (int x = 0; x < 4; x++) {
    float4 v = make_float4(acc[x][0], acc[x][1], acc[x][2], acc[x][3]);
    ((float4*)G2)[(size_t)(bi + a0 + x) * 256 + ((bj + b0) >> 2)] = v;
  }
}

// ---------------------------------------------------------------------------
// fallback: initS fused with cut0 (block 0 scans diag(G), blocks 1.. init S).
__global__ void k_initScut(float* __restrict__ S, const float* __restrict__ G,
                           double* __restrict__ scal)
{
  int b = blockIdx.x;
  int t = threadIdx.x;
  if (b == 0) {
    __shared__ float red[256];
    float m = 0.f;
    for (int p = t; p < NB; p += 256) m = fmaxf(m, G[(size_t)p * NB + p]);
    red[t] = m;
    __syncthreads();
    for (int s = 128; s; s >>= 1) {
      if (t < s) red[t] = fmaxf(red[t], red[t + s]);
      __syncthreads();
    }
    if (t == 0) {
      double c = 0.9 * (double)red[0];
      scal[0] = c;
      scal[1] = c * c;
    }
    return;
  }
  int idx = (b - 1) * 256 + t;
  if (idx < NB * BSUB) {
    unsigned u = (unsigned)(idx + 1) * 2654435761u;
    u ^= u >> 16; u *= 2246822519u; u ^= u >> 13; u *= 3266489917u; u ^= u >> 16;
    S[idx] = ((float)u * (1.f / 4294967296.f)) - 0.5f;
  }
}

// ---------------------------------------------------------------------------
// Fused A@Z with split-K(8) + in-kernel combine (fire-and-forget). A is G or G2.
__global__ __launch_bounds__(256) void k_gzfused(const float* __restrict__ G,
    const float* __restrict__ Z, const float* __restrict__ Zp,
    float* __restrict__ P, float* __restrict__ out, int* __restrict__ cnt,
    const double* __restrict__ cptr, float s1, float s2, float s3)
{
  __shared__ float Gs[32][68];
  __shared__ float Zs[64][84];
  __shared__ int lastf;
  int t = threadIdx.x;
  int r0b = blockIdx.x;
  int r0 = r0b * 32;
  int kz = blockIdx.y;
  int cg_ = t & 15, rg = t >> 4;
  float acc0[5] = {}, acc1[5] = {};
  for (int k0 = kz * 128; k0 < kz * 128 + 128; k0 += 64) {
    __syncthreads();
    #pragma unroll
    for (int s = 0; s < 2; s++) {
      int item = t + s * 256;
      int rr = item >> 4, f4 = item & 15;
      float4 g = ((const float4*)G)[(size_t)(r0 + rr) * 256 + (k0 >> 2) + f4];
      *(float4*)&Gs[rr][f4 * 4] = g;
    }
    #pragma unroll
    for (int s = 0; s < 5; s++) {
      int item = t + s * 256;
      int rr = item / 20, f4 = item % 20;
      float4 z = ((const float4*)Z)[(size_t)(k0 + rr) * 20 + f4];
      *(float4*)&Zs[rr][f4 * 4] = z;
    }
    __syncthreads();
    for (int kk = 0; kk < 64; kk++) {
      float g0 = Gs[rg * 2 + 0][kk];
      float g1 = Gs[rg * 2 + 1][kk];
      float z[5];
      #pragma unroll
      for (int m = 0; m < 5; m++) z[m] = Zs[kk][cg_ * 5 + m];
      #pragma unroll
      for (int m = 0; m < 5; m++) { acc0[m] += g0 * z[m]; acc1[m] += g1 * z[m]; }
    }
  }
  size_t base = (size_t)kz * (NB * BSUB) + (size_t)(r0 + rg * 2) * BSUB + cg_ * 5;
  #pragma unroll
  for (int m = 0; m < 5; m++) P[base + m] = acc0[m];
  #pragma unroll
  for (int m = 0; m < 5; m++) P[base + BSUB + m] = acc1[m];
  __threadfence();
  __syncthreads();
  if (t == 0) {
    int old = atomicAdd(&cnt[r0b], 1);
    lastf = (old == 7) ? 1 : 0;
  }
  __syncthreads();
  if (!lastf) return;
  __threadfence();
  float coef = s1;
  if (cptr) coef = s1 * (float)(2.0 / cptr[0]);
  const float4* P4 = (const float4*)P;
  for (int idx = t; idx < 640; idx += 256) {
    size_t o4 = (size_t)r0 * 20 + idx;
    float4 a = P4[o4];
    #pragma unroll
    for (int u = 1; u < 8; u++) {
      float4 b = P4[(size_t)u * 20480 + o4];
      a.x += b.x; a.y += b.y; a.z += b.z; a.w += b.w;
    }
    float4 z = ((const float4*)Z)[o4];
    float4 o;
    o.x = coef * a.x + s2 * z.x;
    o.y = coef * a.y + s2 * z.y;
    o.z = coef * a.z + s2 * z.z;
    o.w = coef * a.w + s2 * z.w;
    if (s3 != 0.f) {
      float4 zp = ((const float4*)Zp)[o4];
      o.x += s3 * zp.x; o.y += s3 * zp.y; o.z += s3 * zp.z; o.w += s3 * zp.w;
    }
    ((float4*)out)[o4] = o;
  }
  __syncthreads();
  if (t == 0) cnt[r0b] = 0;
}

// ---------------------------------------------------------------------------
// fused X^T Y (16 blocks, partials in CP) + Cholesky/inverse run inline
// by the LAST finisher block.
__global__ __launch_bounds__(512) void k_xtychol(const float* __restrict__ Sa,
    const float* __restrict__ Sb, double* __restrict__ CP,
    float* __restrict__ Rinv, int* __restrict__ cnt)
{
  __shared__ float Xsh[64][BSUB + 1];
  __shared__ float Ysh[64][BSUB + 1];
  __shared__ int lastf;
  int t = threadIdx.x;
  int i0 = blockIdx.x * 64;
  for (int idx = t; idx < 64 * BSUB; idx += 512) {
    int r = idx / BSUB, c = idx % BSUB;
    Xsh[r][c] = Sa[(size_t)(i0 + r) * BSUB + c];
    Ysh[r][c] = Sb[(size_t)(i0 + r) * BSUB + c];
  }
  __syncthreads();
  if (t < 256) {
    int a0 = (t & 15) * 5, b0 = (t >> 4) * 5;
    double acc[5][5] = {};
    for (int dd = 0; dd < 64; dd++) {
      float av[5], bv[5];
      #pragma unroll
      for (int u = 0; u < 5; u++) av[u] = Xsh[dd][a0 + u];
      #pragma unroll
      for (int u = 0; u < 5; u++) bv[u] = Ysh[dd][b0 + u];
      #pragma unroll
      for (int x = 0; x < 5; x++)
        #pragma unroll
        for (int y = 0; y < 5; y++) acc[x][y] += (double)av[x] * (double)bv[y];
    }
    double* outp = CP + (size_t)blockIdx.x * (BSUB * BSUB);
    #pragma unroll
    for (int x = 0; x < 5; x++)
      #pragma unroll
      for (int y = 0; y < 5; y++)
        outp[(size_t)(a0 + x) * BSUB + (b0 + y)] = acc[x][y];
  }
  __threadfence();
  __syncthreads();
  if (t == 0) lastf = (atomicAdd(&cnt[0], 1) == 15) ? 1 : 0;
  __syncthreads();
  if (!lastf) return;
  if (t == 0) cnt[0] = 0;
  __threadfence();
  // ---- cholinv body (512 threads) ----
  __shared__ double R[BSUB][BSUB + 1];
  __shared__ double rownew[2][BSUB];
  __shared__ double dinv[BSUB];
  __shared__ float Xi[BSUB][BSUB + 1];
  for (int idx = t; idx < BSUB * BSUB; idx += 512) {
    double s = 0.0;
    #pragma unroll
    for (int b = 0; b < 16; b++) s += CP[(size_t)b * (BSUB * BSUB) + idx];
    R[idx / BSUB][idx % BSUB] = s;
  }
  __syncthreads();
  double flr0 = 1e-30 * (fabs(R[0][0]) + 1e-280);
  int prevrow = -1;
  int pb = 0;
  int k = 0;
  while (k < BSUB - 1) {
    int nrem = BSUB - 1 - k;
    int total = (nrem * (nrem + 1)) >> 1;
    int cplen = (prevrow >= 0) ? (BSUB - prevrow) : 0;
    double piv = R[k][k];
    if (piv < flr0) piv = flr0;
    double rp = 1.0 / piv;
    bool pair = (k + 1 < BSUB - 1);
    if (pair) {
      double dk1 = R[k][k + 1];
      double p1 = R[k + 1][k + 1] - dk1 * dk1 * rp;
      if (p1 < flr0) p1 = flr0;
      double rp1 = 1.0 / p1;
      for (int idx = t; idx < total + cplen; idx += 512) {
        if (idx < total) {
          float nf = 2.f * (float)nrem + 1.f;
          int a = (int)((nf - sqrtf(nf * nf - 8.f * (float)idx)) * 0.5f);
          while (a > 0 && a * nrem - ((a * (a - 1)) >> 1) > idx) a--;
          while ((a + 1) * nrem - (((a + 1) * a) >> 1) <= idx) a++;
          int off = idx - (a * nrem - ((a * (a - 1)) >> 1));
          int i2 = k + 1 + a, j2 = i2 + off;
          if (a == 0) {
            rownew[pb][j2] = R[k + 1][j2] - dk1 * R[k][j2] * rp;
          } else {
            double v = R[i2][j2] - R[k][i2] * R[k][j2] * rp;
            double R1i = R[k + 1][i2] - dk1 * R[k][i2] * rp;
            double R1j = R[k + 1][j2] - dk1 * R[k][j2] * rp;
            v -= R1i * R1j * rp1;
            R[i2][j2] = v;
          }
        } else {
          int j = prevrow + (idx - total);
          R[prevrow][j] = rownew[pb ^ 1][j];
        }
      }
      __syncthreads();
      prevrow = k + 1; pb ^= 1; k += 2;
    } else {
      for (int idx = t; idx < total + cplen; idx += 512) {
        if (idx < total) {
          float nf = 2.f * (float)nrem + 1.f;
          int a = (int)((nf - sqrtf(nf * nf - 8.f * (float)idx)) * 0.5f);
          while (a > 0 && a * nrem - ((a * (a - 1)) >> 1) > idx) a--;
          while ((a + 1) * nrem - (((a + 1) * a) >> 1) <= idx) a++;
          int off = idx - (a * nrem - ((a * (a - 1)) >> 1));
          int i2 = k + 1 + a, j2 = i2 + off;
          R[i2][j2] -= R[k][i2] * R[k][j2] * rp;
        } else {
          int j = prevrow + (idx - total);
          R[prevrow][j] = rownew[pb ^ 1][j];
        }
      }
      __syncthreads();
      prevrow = -1; k += 1;
    }
  }
  if (prevrow >= 0) {
    for (int j = prevrow + t; j < BSUB; j += 512) R[prevrow][j] = rownew[pb ^ 1][j];
    __syncthreads();
  }
  if (t < BSUB) {
    double piv = R[t][t];
    if (piv < flr0) piv = flr0;
    dinv[t] = 1.0 / sqrt(piv);
  }
  __syncthreads();
  for (int idx = t; idx < BSUB * BSUB; idx += 512) {
    int kk = idx / BSUB, j = idx % BSUB;
    if (j > kk) R[kk][j] *= dinv[kk];
  }
  __syncthreads();
  if (t < BSUB) R[t][t] = 1.0 / dinv[t];
  __syncthreads();
  if (t < BSUB) {
    int j = t;
    Xi[j][j] = (float)dinv[j];
    for (int i = j - 1; i >= 0; i--) {
      double s = 0.0;
      for (int k2 = i + 1; k2 <= j; k2++) s += R[i][k2] * (double)Xi[k2][j];
      Xi[i][j] = (float)(-s * dinv[i]);
    }
    for (int i = j + 1; i < BSUB; i++) Xi[i][j] = 0.f;
  }
  __syncthreads();
  for (int idx = t; idx < BSUB * BSUB; idx += 512)
    Rinv[idx] = Xi[idx / BSUB][idx % BSUB];
}

// out = S @ Rinv   (1024x80 * 80x80)
__global__ __launch_bounds__(256) void k_gemmSR(const float* __restrict__ S,
    const float* __restrict__ Rinv, float* __restrict__ out)
{
  __shared__ float Rsh[BSUB][84];
  int t = threadIdx.x;
  for (int idx = t; idx < BSUB * BSUB; idx += 256)
    Rsh[idx / BSUB][idx % BSUB] = Rinv[idx];
  __syncthreads();
  int r0 = blockIdx.x * 32;
  int r = t >> 3, c0 = (t & 7) * 10;
  float acc[10] = {};
  const float* srow = &S[(size_t)(r0 + r) * BSUB];
  for (int k = 0; k < BSUB; k++) {
    float s = srow[k];
    #pragma unroll
    for (int m = 0; m < 10; m++) acc[m] += s * Rsh[k][c0 + m];
  }
  #pragma unroll
  for (int m = 0; m < 10; m++) out[(size_t)(r0 + r) * BSUB + c0 + m] = acc[m];
}

// ---------------------------------------------------------------------------
// fused X^T Y (16 blocks) + 80x80 Jacobi run inline by the last finisher.
__global__ __launch_bounds__(1024) void k_xtyjac(const float* __restrict__ Sa,
    const float* __restrict__ Sb, double* __restrict__ CP,
    float* __restrict__ Uout, int* __restrict__ perm,
    double* __restrict__ cutout, int sweeps, int withU, int* __restrict__ cnt)
{
  __shared__ float Xsh[64][BSUB + 1];
  __shared__ float Ysh[64][BSUB + 1];
  __shared__ int lastf;
  int t = threadIdx.x;
  int i0 = blockIdx.x * 64;
  for (int idx = t; idx < 64 * BSUB; idx += 1024) {
    int r = idx / BSUB, c = idx % BSUB;
    Xsh[r][c] = Sa[(size_t)(i0 + r) * BSUB + c];
    Ysh[r][c] = Sb[(size_t)(i0 + r) * BSUB + c];
  }
  __syncthreads();
  if (t < 256) {
    int a0 = (t & 15) * 5, b0 = (t >> 4) * 5;
    double acc[5][5] = {};
    for (int dd = 0; dd < 64; dd++) {
      float av[5], bv[5];
      #pragma unroll
      for (int u = 0; u < 5; u++) av[u] = Xsh[dd][a0 + u];
      #pragma unroll
      for (int u = 0; u < 5; u++) bv[u] = Ysh[dd][b0 + u];
      #pragma unroll
      for (int x = 0; x < 5; x++)
        #pragma unroll
        for (int y = 0; y < 5; y++) acc[x][y] += (double)av[x] * (double)bv[y];
    }
    double* outp = CP + (size_t)blockIdx.x * (BSUB * BSUB);
    #pragma unroll
    for (int x = 0; x < 5; x++)
      #pragma unroll
      for (int y = 0; y < 5; y++)
        outp[(size_t)(a0 + x) * BSUB + (b0 + y)] = acc[x][y];
  }
  __threadfence();
  __syncthreads();
  if (t == 0) lastf = (atomicAdd(&cnt[0], 1) == 15) ? 1 : 0;
  __syncthreads();
  if (!lastf) return;
  if (t == 0) cnt[0] = 0;
  __threadfence();
  // ---- jacobi body (1024 threads) ----
  __shared__ float Mb[2][BSUB][BSUB + 1];
  __shared__ float Ut[BSUB][BSUB];
  __shared__ float4 rot[2][NPAIR];
  __shared__ float th[BSUB];
  __shared__ int id[BSUB];
  for (int idx = t; idx < BSUB * BSUB; idx += 1024) {
    double s = 0.0;
    #pragma unroll
    for (int b = 0; b < 16; b++) s += CP[(size_t)b * (BSUB * BSUB) + idx];
    Mb[1][idx / BSUB][idx % BSUB] = (float)s;
    if (withU) Ut[idx / BSUB][idx % BSUB] = ((idx / BSUB) == (idx % BSUB)) ? 1.f : 0.f;
  }
  int pr0 = t / 40, j0 = t - pr0 * 40;
  int pr1 = -1, j1 = 0;
  {
    int i1 = t + 1024;
    if (i1 < 1600) { pr1 = i1 / 40; j1 = i1 - pr1 * 40; }
  }
  int upr0 = -1, um0 = 0, upr1 = -1, um1 = 0;
  if (t >= 40) {
    int u0 = t - 40;              upr0 = u0 / 40; um0 = u0 - upr0 * 40;
    int u1 = t - 40 + 984;
    if (u1 < 1600) { upr1 = u1 / 40; um1 = u1 - upr1 * 40; }
  }
  int rp_ = 0, rq_ = 0;
  if (t < 40) {
    rp_ = (t == 0) ? 0 : 1 + (t - 1) % 79;
    rq_ = 1 + (78 - t) % 79;
  }
  __syncthreads();
  for (int idx = t; idx < BSUB * BSUB; idx += 1024) {
    int i2 = idx / BSUB, j2 = idx % BSUB;
    Mb[0][i2][j2] = 0.5f * (Mb[1][i2][j2] + Mb[1][j2][i2]);
  }
  __syncthreads();
  int nrounds = sweeps * (BSUB - 1);
  int mcur = 0;
  for (int it = 0; it < nrounds; it++) {
    int pb = it & 1;
    float (*Mc)[BSUB + 1] = Mb[mcur];
    float (*Mn)[BSUB + 1] = Mb[mcur ^ 1];
    if (t < 40) {
      int p = rp_, q = rq_;
      if (p > q) { int tmp = p; p = q; q = tmp; }
      float apq = Mc[p][q];
      float c = 1.f, s = 0.f;
      if (fabsf(apq) > 1e-28f) {
        float tau = (Mc[q][q] - Mc[p][p]) / (2.f * apq);
        float tt = copysignf(1.f, tau) / (fabsf(tau) + sqrtf(1.f + tau * tau));
        c = rsqrtf(1.f + tt * tt);
        s = tt * c;
      }
      rot[pb][t] = make_float4(c, s, __int_as_float(p), __int_as_float(q));
      if (t > 0) rp_ = (rp_ == 79) ? 1 : rp_ + 1;
      rq_ = (rq_ == 79) ? 1 : rq_ + 1;
    } else if (withU && it > 0) {
      int ob = pb ^ 1;
      {
        float4 R0 = rot[ob][upr0];
        int p = __float_as_int(R0.z), q = __float_as_int(R0.w);
        float c = R0.x, s = R0.y;
        float2 up = *(float2*)&Ut[p][2 * um0];
        float2 uq = *(float2*)&Ut[q][2 * um0];
        float2 np, nq;
        np.x = c * up.x - s * uq.x;  np.y = c * up.y - s * uq.y;
        nq.x = s * up.x + c * uq.x;  nq.y = s * up.y + c * uq.y;
        *(float2*)&Ut[p][2 * um0] = np;
        *(float2*)&Ut[q][2 * um0] = nq;
      }
      if (upr1 >= 0) {
        float4 R1 = rot[ob][upr1];
        int p = __float_as_int(R1.z), q = __float_as_int(R1.w);
        float c = R1.x, s = R1.y;
        float2 up = *(float2*)&Ut[p][2 * um1];
        float2 uq = *(float2*)&Ut[q][2 * um1];
        float2 np, nq;
        np.x = c * up.x - s * uq.x;  np.y = c * up.y - s * uq.y;
        nq.x = s * up.x + c * uq.x;  nq.y = s * up.y + c * uq.y;
        *(float2*)&Ut[p][2 * um1] = np;
        *(float2*)&Ut[q][2 * um1] = nq;
      }
    }
    __syncthreads();
    {
      float4 Rp = rot[pb][pr0];
      float4 Rj = rot[pb][j0];
      int p = __float_as_int(Rp.z), q = __float_as_int(Rp.w);
      float c = Rp.x, s = Rp.y;
      int k = __float_as_int(Rj.z), k2 = __float_as_int(Rj.w);
      float cj = Rj.x, sj = Rj.y;
      float mpk = Mc[p][k],  mqk = Mc[q][k];
      float mpk2 = Mc[p][k2], mqk2 = Mc[q][k2];
      float rpk  = c * mpk  - s * mqk;
      float rqk  = s * mpk  + c * mqk;
      float rpk2 = c * mpk2 - s * mqk2;
      float rqk2 = s * mpk2 + c * mqk2;
      Mn[p][k]  = cj * rpk - sj * rpk2;
      Mn[q][k]  = cj * rqk - sj * rqk2;
      Mn[p][k2] = sj * rpk + cj * rpk2;
      Mn[q][k2] = sj * rqk + cj * rqk2;
    }
    if (pr1 >= 0) {
      float4 Rp = rot[pb][pr1];
      float4 Rj = rot[pb][j1];
      int p = __float_as_int(Rp.z), q = __float_as_int(Rp.w);
      float c = Rp.x, s = Rp.y;
      int k = __float_as_int(Rj.z), k2 = __float_as_int(Rj.w);
      float cj = Rj.x, sj = Rj.y;
      float mpk = Mc[p][k],  mqk = Mc[q][k];
      float mpk2 = Mc[p][k2], mqk2 = Mc[q][k2];
      float rpk  = c * mpk  - s * mqk;
      float rqk  = s * mpk  + c * mqk;
      float rpk2 = c * mpk2 - s * mqk2;
      float rqk2 = s * mpk2 + c * mqk2;
      Mn[p][k]  = cj * rpk - sj * rpk2;
      Mn[q][k]  = cj * rqk - sj * rqk2;
      Mn[p][k2] = sj * rpk + cj * rpk2;
      Mn[q][k2] = sj * rqk + cj * rqk2;
    }
    __syncthreads();
    mcur ^= 1;
  }
  if (withU) {
    int ob = (nrounds - 1) & 1;
    {
      float4 R0 = rot[ob][pr0];
      int p = __float_as_int(R0.z), q = __float_as_int(R0.w);
      float c = R0.x, s = R0.y;
      float2 up = *(float2*)&Ut[p][2 * j0];
      float2 uq = *(float2*)&Ut[q][2 * j0];
      float2 np, nq;
      np.x = c * up.x - s * uq.x;  np.y = c * up.y - s * uq.y;
      nq.x = s * up.x + c * uq.x;  nq.y = s * up.y + c * uq.y;
      *(float2*)&Ut[p][2 * j0] = np;
      *(float2*)&Ut[q][2 * j0] = nq;
    }
    if (pr1 >= 0) {
      float4 R1 = rot[ob][pr1];
      int p = __float_as_int(R1.z), q = __float_as_int(R1.w);
      float c = R1.x, s = R1.y;
      float2 up = *(float2*)&Ut[p][2 * j1];
      float2 uq = *(float2*)&Ut[q][2 * j1];
      float2 np, nq;
      np.x = c * up.x - s * uq.x;  np.y = c * up.y - s * uq.y;
      nq.x = s * up.x + c * uq.x;  nq.y = s * up.y + c * uq.y;
      *(float2*)&Ut[p][2 * j1] = np;
      *(float2*)&Ut[q][2 * j1] = nq;
    }
    __syncthreads();
  }
  float (*Mf)[BSUB + 1] = Mb[mcur];
  if (t < BSUB) { th[t] = Mf[t][t]; id[t] = t; }
  __syncthreads();
  if (t == 0) {
    for (int a = 1; a < BSUB; a++) {
      float v = th[a]; int ii = id[a]; int b = a - 1;
      while (b >= 0 && th[b] < v) { th[b + 1] = th[b]; id[b + 1] = id[b]; b--; }
      th[b + 1] = v; id[b + 1] = ii;
    }
    double cut = (double)th[BSUB - 1];
    double lo = 0.02 * (double)th[0];
    if (cut < lo) cut = lo;
    double hi = 0.98 * (double)th[63];
    if (cut > hi) cut = hi;
    cutout[0] = cut;
    cutout[1] = cut * cut;
  }
  __syncthreads();
  if (t < BSUB) perm[t] = id[t];
  if (withU)
    for (int idx = t; idx < BSUB * BSUB; idx += 1024) {
      int k = idx / BSUB, p = idx % BSUB;
      Uout[idx] = Ut[p][k];
    }
}

// out[:, c] = S @ U[:, perm[c]], c < 64
__global__ __launch_bounds__(256) void k_compose(const float* __restrict__ S,
    const float* __restrict__ U, const int* __restrict__ perm,
    float* __restrict__ out)
{
  __shared__ float Ush[BSUB][65];
  int t = threadIdx.x;
  for (int idx = t; idx < BSUB * 64; idx += 256) {
    int jj = idx >> 6, c = idx & 63;
    Ush[jj][c] = U[jj * BSUB + perm[c]];
  }
  __syncthreads();
  int r0 = blockIdx.x * 64;
  for (int oidx = t; oidx < 64 * 64; oidx += 256) {
    int r = oidx >> 6, c = oidx & 63;
    float acc = 0.f;
    const float* srow = &S[(size_t)(r0 + r) * BSUB];
    #pragma unroll 8
    for (int j = 0; j < BSUB; j++) acc += srow[j] * Ush[j][c];
    out[(size_t)(r0 + r) * 64 + c] = acc;
  }
}

// ---------------------------------------------------------------------------
// fused: proj[d] = (1/16) * neigh_d @ Vtop, then hout = relu(proj @ W^T + b)
// When Xmat != nullptr, neighbor rows are read LINEARLY from X.
__global__ __launch_bounds__(256) void k_projlin(const float* __restrict__ hl,
    const int* __restrict__ src, const float* __restrict__ Vtop,
    const float* __restrict__ W, const float* __restrict__ bias,
    float* __restrict__ hout, const float* __restrict__ Xmat)
{
  __shared__ float Vsh[64][68];
  __shared__ float Hsh[64][68];
  __shared__ float Psh[64][68];
  int t = threadIdx.x;
  int d0 = blockIdx.x * 64;
  int dd = t & 63, pg = t >> 6;
  float acc[16] = {};
  for (int k = 0; k < 16; k++) {
    __syncthreads();
    for (int item = t; item < 1024; item += 256) {
      int rr = item >> 4, f4 = item & 15;
      *(float4*)&Vsh[rr][f4 * 4] = ((const float4*)Vtop)[(size_t)(k * 64 + rr) * 16 + f4];
      int d = d0 + rr;
      float4 v = make_float4(0.f, 0.f, 0.f, 0.f);
      if (d < NNODES) {
        if (Xmat) {
          v = ((const float4*)Xmat)[(size_t)d * 256 + k * 16 + f4];
        } else {
          int row = (k < EPN) ? src[d * EPN + k] : d;
          v = ((const float4*)hl)[(size_t)row * 16 + f4];
        }
      }
      *(float4*)&Hsh[rr][f4 * 4] = v;
    }
    __syncthreads();
    for (int j = 0; j < 64; j++) {
      float h = Hsh[dd][j];
      #pragma unroll
      for (int m = 0; m < 16; m++) acc[m] += h * Vsh[j][pg * 16 + m];
    }
  }
  __syncthreads();
  #pragma unroll
  for (int m = 0; m < 16; m++) Psh[dd][pg * 16 + m] = acc[m] * (1.f / 16.f);
  for (int item = t; item < 1024; item += 256) {
    int rr = item >> 4, f4 = item & 15;
    *(float4*)&Vsh[rr][f4 * 4] = ((const float4*)W)[(size_t)rr * 16 + f4];
  }
  __syncthreads();
  if (d0 + dd < NNODES) {
    #pragma unroll
    for (int m = 0; m < 16; m++) {
      int o = pg * 16 + m;
      float a = bias[o];
      for (int j = 0; j < 64; j++) a += Psh[dd][j] * Vsh[o][j];
      hout[(size_t)(d0 + dd) * 64 + o] = fmaxf(a, 0.f);
    }
  }
}

__global__ void k_logsoftmax(const float* __restrict__ logits, float* __restrict__ out)
{
  int n = blockIdx.x * 256 + threadIdx.x;
  if (n >= NNODES) return;
  float v[NCLS];
  float mx = -1e30f;
  #pragma unroll
  for (int c = 0; c < NCLS; c++) { v[c] = logits[(size_t)n * NCLS + c]; mx = fmaxf(mx, v[c]); }
  float se = 0.f;
  #pragma unroll
  for (int c = 0; c < NCLS; c++) se += expf(v[c] - mx);
  float lse = mx + logf(se);
  #pragma unroll
  for (int c = 0; c < NCLS; c++) out[(size_t)n * NCLS + c] = v[c] - lse;
}

// ===========================================================================
extern "C" void kernel_launch(void* const* d_in, const int* in_sizes, int n_in,
                              void* d_out, int out_size, void* d_ws, size_t ws_size,
                              hipStream_t stream)
{
  (void)in_sizes; (void)n_in; (void)out_size;
  const float* x = (const float*)d_in[0];
  const int* src = (const int*)d_in[1];
  const float* Wl[3] = { (const float*)d_in[2], (const float*)d_in[4], (const float*)d_in[6] };
  const float* bl[3] = { (const float*)d_in[3], (const float*)d_in[5], (const float*)d_in[7] };
  const float* Wfc = (const float*)d_in[8];
  const float* bfc = (const float*)d_in[9];
  float* outp = (float*)d_out;

  char* w = (char*)d_ws;
  auto alloc = [&](size_t bytes) -> char* {
    char* p = w; w += (bytes + 255) & ~(size_t)255; return p;
  };
  float* hA   = (float*)alloc((size_t)NNODES * 64 * 4);
  float* hB   = (float*)alloc((size_t)NNODES * 64 * 4);
  float* hl   = (float*)alloc((size_t)NNODES * 64 * 4);
  float* T    = (float*)alloc((size_t)NB * NB * 4);
  float* G    = (float*)alloc((size_t)NB * NB * 4);
  float* G2   = (float*)alloc((size_t)NB * NB * 4);
  float* mus  = (float*)alloc(16 * 64 * 4);
  float* Zb[6];
  for (int i = 0; i < 6; i++) Zb[i] = (float*)alloc((size_t)NB * BSUB * 4);
  float* P     = (float*)alloc((size_t)8 * NB * BSUB * 4);
  int* cnt     = (int*)alloc(64 * 4);
  double* CP   = (double*)alloc((size_t)16 * BSUB * BSUB * 8);   // 16 f64 partials
  float* Rinv  = (float*)alloc(BSUB * BSUB * 4);
  float* U     = (float*)alloc(BSUB * BSUB * 4);
  int* perm    = (int*)alloc(BSUB * 4);
  float* Vtop  = (float*)alloc((size_t)NB * 64 * 4);
  double* scal = (double*)alloc(16 * 8);
  // fast-gram extras (used only when workspace permits).
  float* X      = (float*)alloc((size_t)NNODES * NB * 4);                // ~82 MB
  float* TP     = (float*)alloc((size_t)16 * (size_t)NB * NB * 4);       // ~67 MB
  size_t used16 = (size_t)(w - (char*)d_ws);
  (void)alloc((size_t)4 * (size_t)NB * NB * 4);                          // +17 MB
  size_t used20 = (size_t)(w - (char*)d_ws);
  int fastg = (used16 <= ws_size) ? 1 : 0;
  int NS    = (used20 <= ws_size) ? 20 : 16;

  const int GRID_ROWS = (NNODES + 63) / 64;   // 313

  hipMemsetAsync(cnt, 0, 64 * 4, stream);     // combine counters (self-resetting)

  int cur = 0;
  auto gemmGZ = [&](const float* A, const float* Z, const float* Zp, float* o,
                    const double* cptr, float s1, float s2, float s3) {
    hipLaunchKernelGGL(k_gzfused, dim3(32, 8), dim3(256), 0, stream,
                       A, Z, Zp, P, o, cnt, cptr, s1, s2, s3);
  };
  auto chunk2 = [&](int deg, const double* cptr) {
    int a = (cur + 1) % 6, b = (cur + 2) % 6;
    float* bufs[3] = { Zb[cur], Zb[a], Zb[b] };
    int ip = 0, ic = 0, io = 1;
    for (int s = 0; s < deg; s++) {
      if (s == 0)
        gemmGZ(G2, bufs[ic], nullptr, bufs[io], cptr, 1.f, -1.f, 0.f);
      else
        gemmGZ(G2, bufs[ic], bufs[ip], bufs[io], cptr, 2.f, -2.f, -1.f);
      if (s == 0) { ip = 0; ic = 1; io = 2; }
      else { int tmp = ip; ip = ic; ic = io; io = tmp; }
    }
    int sel = (deg - 1) % 3;
    cur = (sel == 0) ? a : (sel == 1) ? b : cur;
  };
  auto cholqr = [&]() {
    hipLaunchKernelGGL(k_xtychol, dim3(16), dim3(512), 0, stream,
                       Zb[cur], Zb[cur], CP, Rinv, cnt + 32);
    int o = (cur + 1) % 6;
    hipLaunchKernelGGL(k_gemmSR, dim3(32), dim3(256), 0, stream, Zb[cur], Rinv, Zb[o]);
    cur = o;
  };
  auto rrmid = [&](double* cutp) {
    int y = (cur + 1) % 6;
    gemmGZ(G, Zb[cur], nullptr, Zb[y], nullptr, 1.f, 0.f, 0.f);   // Y = G S
    hipLaunchKernelGGL(k_xtyjac, dim3(16), dim3(1024), 0, stream,
                       Zb[cur], Zb[y], CP, U, perm, cutp, 2, 0, cnt + 33);
  };
  auto rrfinal = [&](double* cutp) {
    int y = (cur + 1) % 6;
    gemmGZ(G, Zb[cur], nullptr, Zb[y], nullptr, 1.f, 0.f, 0.f);   // Y = G S
    hipLaunchKernelGGL(k_xtyjac, dim3(16), dim3(1024), 0, stream,
                       Zb[cur], Zb[y], CP, U, perm, cutp, 5, 1, cnt + 33);
    hipLaunchKernelGGL(k_compose, dim3(16), dim3(256), 0, stream,
                       Zb[cur], U, perm, Vtop);
  };

  const float* hin = x;
  float* hout = hA;
  for (int l = 0; l < 3; l++) {
    hipLaunchKernelGGL(k_linT, dim3(GRID_ROWS), dim3(256), 0, stream,
                       hin, Wl[l], (const float*)nullptr, hl, 64, 0);
    hipMemsetAsync(mus, 0, 16 * 64 * 4, stream);
    if (fastg) {
      hipLaunchKernelGGL(k_buildX, dim3(GRID_ROWS), dim3(256), 0, stream,
                         hl, src, X, mus);
      hipLaunchKernelGGL(k_syrkX, dim3(36 * NS), dim3(256), 0, stream,
                         X, TP, NNODES / NS, mus);
      hipLaunchKernelGGL(k_assembleG16, dim3(4096), dim3(256), 0, stream,
                         TP, G, NS, 1.f / 256.f,
                         (float*)nullptr, (const float*)nullptr, (double*)nullptr);
      // G2 = G^T G via the same SYRK (G symmetric; identical row layout).
      hipLaunchKernelGGL(k_syrkX, dim3(36 * 4), dim3(256), 0, stream,
                         G, TP, NB / 4, (const float*)nullptr);
      cur = 0;
      // assemble G2 + fold in cut0 (block 4096) and S-init (blocks 4097..)
      hipLaunchKernelGGL(k_assembleG16, dim3(4096 + 1 + 320), dim3(256), 0, stream,
                         TP, G2, 4, 1.f, Zb[cur], G, scal);
    } else {
      hipLaunchKernelGGL(k_meanslot, dim3(16, 8), dim3(256), 0, stream, hl, src, mus);
      hipMemsetAsync(T, 0, (size_t)NB * NB * 4, stream);
      hipLaunchKernelGGL(k_gram, dim3(136, 5), dim3(256), 0, stream, hl, src, mus, T);
      hipLaunchKernelGGL(k_assembleG, dim3(4096), dim3(256), 0, stream, T, G);
      hipLaunchKernelGGL(k_gemmG2, dim3(16, 16), dim3(256), 0, stream, G, G2);
      cur = 0;
      hipLaunchKernelGGL(k_initScut, dim3(1 + (NB * BSUB + 255) / 256), dim3(256), 0,
                         stream, Zb[cur], G, scal);
    }
    chunk2(6, &scal[1]); cholqr();          // T12 filter
    rrmid(&scal[2]);                        // writes scal[2]=cut, scal[3]=cut^2
    chunk2(7, &scal[3]); cholqr();          // T14
    chunk2(7, &scal[3]); cholqr();          // T14
    rrfinal(&scal[4]);
    hipLaunchKernelGGL(k_projlin, dim3(GRID_ROWS), dim3(256), 0, stream,
                       hl, src, Vtop, Wl[l], bl[l], hout,
                       fastg ? (const float*)X : (const float*)nullptr);
    hin = hout;
    hout = (hout == hA) ? hB : hA;
  }
  hipLaunchKernelGGL(k_linT, dim3(GRID_ROWS), dim3(256), 0, stream,
                     hin, Wfc, bfc, hl, NCLS, 0);
  hipLaunchKernelGGL(k_logsoftmax, dim3((NNODES + 255) / 256), dim3(256), 0, stream,
                     hl, outp);
}